// Round 20
// baseline (748.270 us; speedup 1.0000x reference)
//
#include <hip/hip_runtime.h>
#include <math.h>

typedef short short8 __attribute__((ext_vector_type(8)));
typedef float f32x4 __attribute__((ext_vector_type(4)));

#define DEV static __device__ __forceinline__
#define NBLK 256   // blocks for bucket passes A/B

// ---- fp32 -> bf16 round-to-nearest-even; and hi/lo split -------------------
DEV unsigned int bf16h(float x) {
  unsigned int u = __float_as_uint(x);
  return (u + 0x7FFFu + ((u >> 16) & 1u)) >> 16;
}
DEV void split2(float x, unsigned int& h, unsigned int& l) {
  h = bf16h(x);
  float hf = __uint_as_float(h << 16);
  l = bf16h(x - hf);
}
DEV float b2f(unsigned int u) { return __uint_as_float(u << 16); }

// fragment-major W image index (ushort units) for element (c,k) of a
// [C=128 cols][K] transposed weight. Per 64-k subtile s (8192 shorts):
// [cg 0..3][ks 0..1][fc 0..1][lane 0..63][j 0..7] where
// col = cg*32 + fc*16 + (lane&15), k = s*64 + (ks*4 + (lane>>4))*8 + j.
DEV int fragidx(int c, int k) {
  int s = k >> 6, kk = k & 63;
  int ch = kk >> 3;            // 0..7 = ks*4 + g
  int ks = ch >> 2, g = ch & 3;
  int j = kk & 7;
  int cg = c >> 5, cc = c & 31;
  int fc = cc >> 4, rl = cc & 15;
  int lane = g * 16 + rl;
  return s * 8192 + cg * 2048 + ks * 1024 + fc * 512 + lane * 8 + j;
}

// ---------------------------------------------------------------------------
// CSR build via 128-row bucket sort (cross-XCD-write-friendly).
// pairs packed: src in bits 0..19, bucket-local dst in bits 20..26.
// ---------------------------------------------------------------------------
__global__ __launch_bounds__(1024) void bucketA(const int* __restrict__ dst,
                                                int* __restrict__ histG,
                                                int E, int chunk, int NB) {
  __shared__ int lh[1024];
  const int t = threadIdx.x;
  for (int i = t; i < NB; i += 1024) lh[i] = 0;
  __syncthreads();
  int s = blockIdx.x * chunk;
  int e = s + chunk; if (e > E) e = E;
  for (int i = s + t; i < e; i += 1024) atomicAdd(&lh[dst[i] >> 7], 1);
  __syncthreads();
  for (int b = t; b < NB; b += 1024) histG[b * NBLK + blockIdx.x] = lh[b];
}

__global__ __launch_bounds__(1024) void bucketS(int* __restrict__ histG,
                                                int* __restrict__ bucketStart,
                                                int NB) {
  __shared__ int btot[1024];
  __shared__ int wsum[16];
  const int t = threadIdx.x, lane = t & 63, wv = t >> 6;
  for (int b = wv; b < NB; b += 16) {
    int carry = 0;
#pragma unroll
    for (int c = 0; c < NBLK / 64; ++c) {
      int idx = b * NBLK + c * 64 + lane;
      int v = histG[idx];
      int x = v;
#pragma unroll
      for (int d = 1; d < 64; d <<= 1) {
        int y = __shfl_up(x, d);
        if (lane >= d) x += y;
      }
      histG[idx] = carry + (x - v);
      carry += __shfl(x, 63);
    }
    if (lane == 0) btot[b] = carry;
  }
  __syncthreads();
  int v = (t < NB) ? btot[t] : 0;
  int x = v;
#pragma unroll
  for (int d = 1; d < 64; d <<= 1) {
    int y = __shfl_up(x, d);
    if (lane >= d) x += y;
  }
  if (lane == 63) wsum[wv] = x;
  __syncthreads();
  if (wv == 0) {
    int y = (lane < 16) ? wsum[lane] : 0;
#pragma unroll
    for (int d = 1; d < 16; d <<= 1) {
      int z = __shfl_up(y, d);
      if (lane >= d) y += z;
    }
    if (lane < 16) wsum[lane] = y;
  }
  __syncthreads();
  int wbase = (wv > 0) ? wsum[wv - 1] : 0;
  int incl = wbase + x;
  if (t < NB) bucketStart[t] = incl - v;
  if (t == NB - 1) bucketStart[NB] = incl;
}

__global__ __launch_bounds__(1024) void bucketB(const int* __restrict__ src,
                                                const int* __restrict__ dstA,
                                                const int* __restrict__ histG,
                                                const int* __restrict__ bucketStart,
                                                unsigned int* __restrict__ pairs,
                                                int E, int chunk, int NB) {
  __shared__ int lbase[1024];
  __shared__ int lcnt[1024];
  const int t = threadIdx.x;
  for (int i = t; i < NB; i += 1024) {
    lbase[i] = bucketStart[i] + histG[i * NBLK + blockIdx.x];
    lcnt[i] = 0;
  }
  __syncthreads();
  int s = blockIdx.x * chunk;
  int e = s + chunk; if (e > E) e = E;
  for (int i = s + t; i < e; i += 1024) {
    int d = dstA[i];
    int b = d >> 7;
    int r = atomicAdd(&lcnt[b], 1);
    pairs[lbase[b] + r] = (unsigned int)src[i] | ((unsigned int)(d & 127) << 20);
  }
}

__global__ __launch_bounds__(256) void bucketC(const unsigned int* __restrict__ pairs,
                                               const int* __restrict__ bucketStart,
                                               int* __restrict__ rowptr,
                                               int* __restrict__ colidx,
                                               float* __restrict__ n1,
                                               float* __restrict__ n2,
                                               int N, int E) {
  __shared__ int degs[128];
  __shared__ int incl[128];
  __shared__ int cur[128];
  const int t = threadIdx.x, lane = t & 63;
  const int b = blockIdx.x;
  const int lo = b << 7;
  const int s0 = bucketStart[b], s1 = bucketStart[b + 1];
  if (t < 128) degs[t] = 0;
  __syncthreads();
  for (int i = s0 + t; i < s1; i += 256) atomicAdd(&degs[pairs[i] >> 20], 1);
  __syncthreads();
  int d = 0, x = 0;
  if (t < 128) {
    d = degs[t];
    x = d;
#pragma unroll
    for (int dd = 1; dd < 64; dd <<= 1) {
      int y = __shfl_up(x, dd);
      if (lane >= dd) x += y;
    }
    incl[t] = x;
  }
  __syncthreads();
  if (t >= 64 && t < 128) incl[t] += incl[63];
  __syncthreads();
  if (t < 128) {
    int excl = incl[t] - d;
    int row = lo + t;
    if (row < N) {
      rowptr[row] = s0 + excl;
      int dd2 = d < 1 ? 1 : d;
      float fd = (float)dd2;
      float r = 1.0f / sqrtf(fd);
      n1[row] = r;
      n2[row] = r / fd;
    }
    cur[t] = excl;
  }
  __syncthreads();
  for (int i = s0 + t; i < s1; i += 256) {
    unsigned int p = pairs[i];
    int off = atomicAdd(&cur[p >> 20], 1);
    colidx[s0 + off] = (int)(p & 0xFFFFFu);
  }
  if (b == 0 && t == 0) rowptr[N] = E;
}

// ---------------------------------------------------------------------------
// agg gather: 8-wide batched; output written PRE-SWIZZLED in the sage_mm
// LDS-image layout: per 64-row tile T, subtile s (k0=s*64) is an 8KB image;
// element (r,k) at byte T*16384 + s*8192 + r*128 + (((k>>3)^(r&7))<<4)+(k&7)*2.
// Wave writes one row: lane l -> cols (2l,2l+1).
// ---------------------------------------------------------------------------
__global__ __launch_bounds__(256) void agg_kernel(
    const unsigned short* __restrict__ hn, const int* __restrict__ rowptr,
    const int* __restrict__ colidx, const float* __restrict__ n2,
    unsigned short* __restrict__ aggswz, int N) {
  int wid = (blockIdx.x * 256 + threadIdx.x) >> 6;
  int lane = threadIdx.x & 63;
  if (wid >= N) return;
  int s = rowptr[wid], e = rowptr[wid + 1];
  const unsigned int* h2 = (const unsigned int*)hn;  // 2 bf16 / uint, 64/row
  float ax[4] = {0.f, 0.f, 0.f, 0.f};
  float ay[4] = {0.f, 0.f, 0.f, 0.f};
  for (int i = s; i < e; i += 8) {
    int c[8];
#pragma unroll
    for (int j = 0; j < 8; ++j) {
      int idx = i + j;
      c[j] = colidx[idx < e ? idx : e - 1];
    }
    unsigned int v[8];
#pragma unroll
    for (int j = 0; j < 8; ++j) v[j] = h2[(size_t)c[j] * 64 + lane];
#pragma unroll
    for (int j = 0; j < 8; ++j) {
      bool ok = (i + j) < e;
      ax[j & 3] += ok ? b2f(v[j] & 0xffffu) : 0.f;
      ay[j & 3] += ok ? __uint_as_float(v[j] & 0xffff0000u) : 0.f;
    }
  }
  float m = n2[wid];
  float axs = ((ax[0] + ax[1]) + (ax[2] + ax[3])) * m;
  float ays = ((ay[0] + ay[1]) + (ay[2] + ay[3])) * m;
  unsigned int packed = bf16h(axs) | (bf16h(ays) << 16);
  int T = wid >> 6, r = wid & 63;
  int sb = lane >> 5, lq = lane & 31;           // k = 2*lq within subtile
  int ch = lq >> 2;                             // (2*lq)>>3
  size_t off = (size_t)T * 16384 + sb * 8192 + r * 128 +
               ((ch ^ (r & 7)) << 4) + (lq & 3) * 4;
  *(unsigned int*)((char*)aggswz + off) = packed;
}

// ---------------------------------------------------------------------------
// Weight prep, single launch: transposed + hi/lo split into fragment-major
// images (per-wave coalesced 16B/lane register loads in sage_mm).
// ---------------------------------------------------------------------------
__global__ __launch_bounds__(256) void prep_all(
    const float* __restrict__ encW, const float* __restrict__ W1,
    const float* __restrict__ W2, unsigned short* __restrict__ encWh,
    unsigned short* __restrict__ encWl, unsigned short* __restrict__ W1th,
    unsigned short* __restrict__ W1tl, unsigned short* __restrict__ W2th,
    unsigned short* __restrict__ W2tl, int L) {
  int t = blockIdx.x * 256 + threadIdx.x;
  const int n1e = 16384;
  const int n2e = n1e + L * 32768;
  const int n3e = n2e + L * 16384;
  unsigned int h, l;
  if (t < n1e) {
    int c = t >> 7, k = t & 127;
    split2(encW[k * 128 + c], h, l);
    int di = fragidx(c, k);
    encWh[di] = (unsigned short)h; encWl[di] = (unsigned short)l;
  } else if (t < n2e) {
    int u = t - n1e;
    int ll = u >> 15, w = u & 32767;
    int c = w >> 8, k = w & 255;
    split2(W1[(size_t)ll * 32768 + k * 128 + c], h, l);
    int di = ll * 32768 + fragidx(c, k);
    W1th[di] = (unsigned short)h; W1tl[di] = (unsigned short)l;
  } else if (t < n3e) {
    int u = t - n2e;
    int ll = u >> 14, w = u & 16383;
    int c = w >> 7, k = w & 127;
    split2(W2[(size_t)ll * 16384 + k * 128 + c], h, l);
    int di = ll * 16384 + fragidx(c, k);
    W2th[di] = (unsigned short)h; W2tl[di] = (unsigned short)l;
  }
}

// ---------------------------------------------------------------------------
// Fused MFMA kernel: 256 threads (4 waves), 64-row x 128-col tile, BK=64.
// Double-buffered As (2 x 8KB). h subtiles: issue-early/write-late reg path.
// agg subtiles: async global_load_lds from the pre-swizzled agg image
// (linear LDS dest = linear read of swizzled source), issued right after the
// preceding barrier so the DMA drains under the intervening kloop.
// W fragments register-loaded from L2-hot fragment-major images.
// KIND 0: h = bf16(fp32A @ W1 + b1). KIND 1: full fused layer (+ hn emit).
// ---------------------------------------------------------------------------
template <int KIND>
__global__ __launch_bounds__(256, 8) void sage_mm(
    const float* __restrict__ Af, const unsigned short* __restrict__ Ab,
    const unsigned short* __restrict__ aggswz,
    const unsigned short* __restrict__ W1h, const unsigned short* __restrict__ W1l,
    const unsigned short* __restrict__ W2h, const unsigned short* __restrict__ W2l,
    const float* __restrict__ b1, const float* __restrict__ b2,
    const float* __restrict__ n1f,
    unsigned short* __restrict__ outb, unsigned short* __restrict__ hnout,
    int M) {
  __shared__ unsigned short lds[64 * 128];   // 16KB: buf0|buf1; Cs overlay
  unsigned short* buf0 = lds;
  unsigned short* buf1 = lds + 64 * 64;

  const int t = threadIdx.x;
  const int lane = t & 63;
  const int w = t >> 6;              // 0..3 = col-group
  const int rl = lane & 15, g = lane >> 4;
  const int cbase = w * 32;
  const int rowbase = blockIdx.x * 64;

  // ---- h staging split: load (to regs) / write (to LDS buf) ---------------
  auto loadAb = [&](const unsigned short* __restrict__ src, int k0, int4* v) {
    int r = t >> 2, kc = (t & 3) * 16;
    int grow = rowbase + r;
    const int4* s = (const int4*)(src + (size_t)grow * 128 + k0 + kc);
    v[0] = (grow < M) ? s[0] : make_int4(0, 0, 0, 0);
    v[1] = (grow < M) ? s[1] : make_int4(0, 0, 0, 0);
  };
  auto writeAb = [&](unsigned short* dst, const int4* v) {
    int r = t >> 2, kc = (t & 3) * 16;
#pragma unroll
    for (int j = 0; j < 2; ++j) {
      int ch = (kc >> 3) + j;
      int off = r * 128 + ((ch ^ (r & 7)) << 4);
      *(int4*)((char*)dst + off) = v[j];
    }
  };
  auto loadAf = [&](const float* __restrict__ src, int k0, float4* v) {
    int r = t >> 2, kc = (t & 3) * 16;
    int grow = rowbase + r;
    const float4* s = (const float4*)(src + (size_t)grow * 128 + k0 + kc);
#pragma unroll
    for (int j = 0; j < 4; ++j)
      v[j] = (grow < M) ? s[j] : make_float4(0.f, 0.f, 0.f, 0.f);
  };
  auto writeAf = [&](unsigned short* dst, const float4* v) {
    int r = t >> 2, kc = (t & 3) * 16;
#pragma unroll
    for (int j = 0; j < 4; ++j) {
      unsigned int h0 = bf16h(v[j].x), h1 = bf16h(v[j].y);
      unsigned int h2 = bf16h(v[j].z), h3 = bf16h(v[j].w);
      int k = kc + j * 4;
      int off = r * 128 + (((k >> 3) ^ (r & 7)) << 4) + (k & 7) * 2;
      *(int2*)((char*)dst + off) =
          make_int2((int)(h0 | (h1 << 16)), (int)(h2 | (h3 << 16)));
    }
  };

  // async DMA of one pre-swizzled agg subtile image (8KB) into dstbuf
  auto gllA = [&](unsigned short* dstbuf, int sub) {
    const char* gp = (const char*)aggswz + (size_t)blockIdx.x * 16384 +
                     (size_t)sub * 8192;
    int o = w * 2048 + lane * 16;
#if defined(__has_builtin) && __has_builtin(__builtin_amdgcn_global_load_lds)
    __builtin_amdgcn_global_load_lds(gp + o, (char*)dstbuf + w * 2048, 16, 0, 0);
    __builtin_amdgcn_global_load_lds(gp + o + 1024,
                                     (char*)dstbuf + w * 2048 + 1024, 16, 0, 0);
#else
    *(int4*)((char*)dstbuf + o) = *(const int4*)(gp + o);
    *(int4*)((char*)dstbuf + o + 1024) = *(const int4*)(gp + o + 1024);
#endif
  };

  f32x4 acc[4][2];
  auto zacc = [&]() {
#pragma unroll
    for (int i = 0; i < 4; ++i)
#pragma unroll
      for (int j = 0; j < 2; ++j) {
        f32x4 z = {0.f, 0.f, 0.f, 0.f};
        acc[i][j] = z;
      }
  };

  // kloop over one staged A-subtile in `as`; W fragments from global (L2-hot)
  auto kloop = [&](const unsigned short* imgh, const unsigned short* imgl,
                   int sub, const unsigned short* as) {
    const unsigned short* bh0 = imgh + sub * 8192 + w * 2048 + lane * 8;
    const unsigned short* bl0 = imgl + sub * 8192 + w * 2048 + lane * 8;
#pragma unroll
    for (int ks = 0; ks < 2; ++ks) {
      short8 aH[4], bH[2], bL[2];
#pragma unroll
      for (int fc = 0; fc < 2; ++fc) {
        bH[fc] = *(const short8*)(bh0 + ks * 1024 + fc * 512);
        bL[fc] = *(const short8*)(bl0 + ks * 1024 + fc * 512);
      }
#pragma unroll
      for (int fr = 0; fr < 4; ++fr) {
        int row = fr * 16 + rl;
        int off = row * 128 + (((ks * 4 + g) ^ (row & 7)) << 4);
        aH[fr] = *(const short8*)((const char*)as + off);
      }
#pragma unroll
      for (int fr = 0; fr < 4; ++fr)
#pragma unroll
        for (int fc = 0; fc < 2; ++fc) {
          acc[fr][fc] = __builtin_amdgcn_mfma_f32_16x16x32_bf16(
              aH[fr], bH[fc], acc[fr][fc], 0, 0, 0);
          acc[fr][fc] = __builtin_amdgcn_mfma_f32_16x16x32_bf16(
              aH[fr], bL[fc], acc[fr][fc], 0, 0, 0);
        }
    }
  };

  // z = relu(a + b1) staged (bf16) into `dst` for cols [c0,c0+64)
  auto zstage = [&](int c0, const f32x4 (&a)[4][2], unsigned short* dst) {
#pragma unroll
    for (int fc = 0; fc < 2; ++fc) {
      int col = cbase + fc * 16 + rl;
      unsigned int lc = (unsigned int)(col - c0);
      if (lc < 64u) {
        float bb = b1[col];
#pragma unroll
        for (int fr = 0; fr < 4; ++fr)
#pragma unroll
          for (int q = 0; q < 4; ++q) {
            int row = fr * 16 + g * 4 + q;
            float z = fmaxf(a[fr][fc][q] + bb, 0.f);
            int off = row * 128 + (((lc >> 3) ^ (row & 7)) << 4) + (lc & 7) * 2;
            *(unsigned short*)((char*)dst + off) = (unsigned short)bf16h(z);
          }
      }
    }
  };

  zacc();
  if (KIND == 0) {
    float4 vf[4];
    loadAf(Af, 0, vf); writeAf(buf0, vf);
    __syncthreads();
    loadAf(Af, 64, vf);                 // issue early
    kloop(W1h, W1l, 0, buf0);           // compute under load latency
    writeAf(buf1, vf);                  // write late
    __syncthreads();
    kloop(W1h, W1l, 1, buf1);
  } else {
    int4 va[2];
    loadAb(Ab, 0, va); writeAb(buf0, va);
    __syncthreads();
    loadAb(Ab, 64, va);
    kloop(W1h, W1l, 0, buf0);
    writeAb(buf1, va);
    __syncthreads();
    gllA(buf0, 0);                      // async DMA under next kloop
    kloop(W1h, W1l, 1, buf1);
    __syncthreads();                    // drains vmcnt incl. DMA
    gllA(buf1, 1);
    kloop(W1h, W1l, 2, buf0);
    __syncthreads();
    kloop(W1h, W1l, 3, buf1);           // GEMM1 complete in acc

    f32x4 acc1[4][2];
#pragma unroll
    for (int i = 0; i < 4; ++i)
#pragma unroll
      for (int j = 0; j < 2; ++j) acc1[i][j] = acc[i][j];
    zacc();
    zstage(0, acc1, buf0);              // buf0 free (last read P2)
    __syncthreads();
    zstage(64, acc1, buf1);             // buf1 reads done (barrier above)
    kloop(W2h, W2l, 0, buf0);           // concurrent: reads buf0
    __syncthreads();
    kloop(W2h, W2l, 1, buf1);
  }

  // ---- epilogue: stage C in LDS (16KB overlay) -> coalesced writes ---------
  __syncthreads();
  unsigned short* Cs = lds;
  const float* bias = (KIND == 0) ? b1 : b2;
#pragma unroll
  for (int fc = 0; fc < 2; ++fc) {
    int col = cbase + fc * 16 + rl;
    float bb = bias[col];
#pragma unroll
    for (int fr = 0; fr < 4; ++fr)
#pragma unroll
      for (int q = 0; q < 4; ++q) {
        int row = fr * 16 + g * 4 + q;
        float val = acc[fr][fc][q] + bb;
        if (KIND == 1) val = fmaxf(val, 0.f);
        Cs[row * 128 + col] = (unsigned short)bf16h(val);
      }
  }
  __syncthreads();
#pragma unroll
  for (int p = 0; p < 4; ++p) {
    int bo = p * 4096 + t * 16;
    int row = bo >> 8;
    int grow = rowbase + row;
    if (grow >= M) continue;
    int4 z4 = *(const int4*)((const char*)Cs + bo);
    int* zp = (int*)&z4;
    if (KIND == 1) {
      int4 a4 = *(const int4*)((const char*)Ab + (size_t)grow * 256 + (bo & 255));
      const int* ap = (const int*)&a4;
#pragma unroll
      for (int u = 0; u < 4; ++u) {
        unsigned int za = (unsigned int)zp[u], aa = (unsigned int)ap[u];
        float vlo = b2f(za & 0xffffu) + b2f(aa & 0xffffu);
        float vhi = __uint_as_float(za & 0xffff0000u) +
                    __uint_as_float(aa & 0xffff0000u);
        zp[u] = (int)(bf16h(vlo) | (bf16h(vhi) << 16));
      }
    }
    *(int4*)((char*)outb + (size_t)grow * 256 + (bo & 255)) = z4;
    if (hnout) {  // hn = bf16(h * n1[grow]); skipped on last layer
      float n1r = n1f[grow];
      int4 hn4;
      int* hp = (int*)&hn4;
#pragma unroll
      for (int u = 0; u < 4; ++u) {
        unsigned int za = (unsigned int)zp[u];
        float vlo = b2f(za & 0xffffu) * n1r;
        float vhi = __uint_as_float(za & 0xffff0000u) * n1r;
        hp[u] = (int)(bf16h(vlo) | (bf16h(vhi) << 16));
      }
      *(int4*)((char*)hnout + (size_t)grow * 256 + (bo & 255)) = hn4;
    }
  }
}

// ---------------------------------------------------------------------------
// Pooling + readout (h in bf16)
// ---------------------------------------------------------------------------
__global__ __launch_bounds__(256) void pool_partial(
    const unsigned short* __restrict__ h, float* __restrict__ partial, int N) {
  int col = threadIdx.x & 127;
  int stream = blockIdx.x * 2 + (threadIdx.x >> 7);
  float s = 0.f;
  for (int r = stream; r < N; r += 512)
    s += b2f((unsigned int)h[(size_t)r * 128 + col]);
  partial[stream * 128 + col] = s;
}

__global__ __launch_bounds__(256) void readout_kernel(
    const float* __restrict__ partial, const float* __restrict__ rW1,
    const float* __restrict__ rb1, const float* __restrict__ rW2,
    const float* __restrict__ rb2, const float* __restrict__ rW3,
    const float* __restrict__ rb3, float* __restrict__ outp, int N) {
  __shared__ float pooled[128];
  __shared__ float x1[64];
  __shared__ float x2[32];
  int t = threadIdx.x;
  if (t < 128) {
    float s = 0.f;
    for (int i = 0; i < 512; ++i) s += partial[i * 128 + t];
    pooled[t] = s / (float)N;
  }
  __syncthreads();
  if (t < 64) {
    float s = rb1[t];
    for (int k = 0; k < 128; ++k) s = fmaf(pooled[k], rW1[k * 64 + t], s);
    x1[t] = fmaxf(s, 0.f);
  }
  __syncthreads();
  if (t < 32) {
    float s = rb2[t];
    for (int k = 0; k < 64; ++k) s = fmaf(x1[k], rW2[k * 32 + t], s);
    x2[t] = fmaxf(s, 0.f);
  }
  __syncthreads();
  if (t < 10) {
    float s = rb3[t];
    for (int k = 0; k < 32; ++k) s = fmaf(x2[k], rW3[k * 10 + t], s);
    outp[t] = s;
  }
}

extern "C" void kernel_launch(void* const* d_in, const int* in_sizes, int n_in,
                              void* d_out, int out_size, void* d_ws, size_t ws_size,
                              hipStream_t stream) {
  const float* h_in  = (const float*)d_in[0];
  const int*   src   = (const int*)d_in[1];
  const int*   dst   = (const int*)d_in[2];
  const float* enc_W = (const float*)d_in[3];
  const float* enc_b = (const float*)d_in[4];
  const float* W1    = (const float*)d_in[5];
  const float* b1    = (const float*)d_in[6];
  const float* W2    = (const float*)d_in[7];
  const float* b2    = (const float*)d_in[8];
  const float* rW1   = (const float*)d_in[9];
  const float* rb1   = (const float*)d_in[10];
  const float* rW2   = (const float*)d_in[11];
  const float* rb2   = (const float*)d_in[12];
  const float* rW3   = (const float*)d_in[13];
  const float* rb3   = (const float*)d_in[14];

  const int N = in_sizes[0] / 128;
  const int E = in_sizes[1];
  const int L = in_sizes[6] / 128;
  const int NB = (N + 127) >> 7;
  const int chunk = (E + NBLK - 1) / NBLK;
  const int gblocks = (N + 63) / 64;

  char* ws = (char*)d_ws;
  size_t off = 0;
  auto alloc = [&](size_t bytes) {
    char* p = ws + off;
    off = (off + bytes + 511) & ~(size_t)511;
    return p;
  };
  unsigned short* h    = (unsigned short*)alloc((size_t)N * 128 * 2);
  unsigned short* hn   = (unsigned short*)alloc((size_t)N * 128 * 2);
  unsigned short* aggs = (unsigned short*)alloc((size_t)gblocks * 16384);
  int* rowptr     = (int*)alloc((size_t)(N + 1) * 4);
  int* colidx     = (int*)alloc((size_t)E * 4);
  float* n1       = (float*)alloc((size_t)N * 4);
  float* n2       = (float*)alloc((size_t)N * 4);
  int* histG      = (int*)alloc((size_t)NB * NBLK * 4);
  int* bucketStart= (int*)alloc((size_t)(NB + 1) * 4);
  float* partial  = (float*)alloc((size_t)512 * 128 * 4);
  unsigned short* encWh = (unsigned short*)alloc(16384 * 2);
  unsigned short* encWl = (unsigned short*)alloc(16384 * 2);
  unsigned short* W1th  = (unsigned short*)alloc((size_t)L * 32768 * 2);
  unsigned short* W1tl  = (unsigned short*)alloc((size_t)L * 32768 * 2);
  unsigned short* W2th  = (unsigned short*)alloc((size_t)L * 16384 * 2);
  unsigned short* W2tl  = (unsigned short*)alloc((size_t)L * 16384 * 2);
  unsigned int* pairs = (unsigned int*)alloc((size_t)E * 4);  // CSR scratch
  (void)ws_size; (void)n_in; (void)out_size;

  {
    int tot = 16384 + L * 32768 + L * 16384;
    prep_all<<<(tot + 255) / 256, 256, 0, stream>>>(
        enc_W, W1, W2, encWh, encWl, W1th, W1tl, W2th, W2tl, L);
  }

  bucketA<<<NBLK, 1024, 0, stream>>>(dst, histG, E, chunk, NB);
  bucketS<<<1, 1024, 0, stream>>>(histG, bucketStart, NB);
  bucketB<<<NBLK, 1024, 0, stream>>>(src, dst, histG, bucketStart, pairs, E,
                                     chunk, NB);
  bucketC<<<NB, 256, 0, stream>>>(pairs, bucketStart, rowptr, colidx, n1, n2, N, E);

  sage_mm<0><<<gblocks, 256, 0, stream>>>(h_in, nullptr, nullptr, encWh, encWl,
                                          nullptr, nullptr, enc_b, nullptr,
                                          n1, h, hn, N);
  for (int l = 0; l < L; ++l) {
    agg_kernel<<<(N + 3) / 4, 256, 0, stream>>>(hn, rowptr, colidx, n2, aggs, N);
    sage_mm<1><<<gblocks, 256, 0, stream>>>(
        nullptr, h, aggs, W1th + (size_t)l * 32768, W1tl + (size_t)l * 32768,
        W2th + (size_t)l * 16384, W2tl + (size_t)l * 16384,
        b1 + l * 128, b2 + l * 128, n1, h,
        (l == L - 1) ? nullptr : hn, N);
  }
  pool_partial<<<256, 256, 0, stream>>>(h, partial, N);
  readout_kernel<<<1, 256, 0, stream>>>(partial, rW1, rb1, rW2, rb2, rW3, rb3,
                                        (float*)d_out, N);
}

// Round 22
// 651.733 us; speedup vs baseline: 1.1481x; 1.1481x over previous
//
#include <hip/hip_runtime.h>
#include <math.h>

typedef short short8 __attribute__((ext_vector_type(8)));
typedef float f32x4 __attribute__((ext_vector_type(4)));

#define DEV static __device__ __forceinline__
#define NBLK 256   // blocks for bucket passes A/B

// ---- fp32 -> bf16 round-to-nearest-even; and hi/lo split -------------------
DEV unsigned int bf16h(float x) {
  unsigned int u = __float_as_uint(x);
  return (u + 0x7FFFu + ((u >> 16) & 1u)) >> 16;
}
DEV void split2(float x, unsigned int& h, unsigned int& l) {
  h = bf16h(x);
  float hf = __uint_as_float(h << 16);
  l = bf16h(x - hf);
}
DEV float b2f(unsigned int u) { return __uint_as_float(u << 16); }

// fragment-major W image index (ushort units) for element (c,k) of a
// [C=128 cols][K] transposed weight. Per 64-k subtile s (8192 shorts):
// [cg 0..3][ks 0..1][fc 0..1][lane 0..63][j 0..7] where
// col = cg*32 + fc*16 + (lane&15), k = s*64 + (ks*4 + (lane>>4))*8 + j.
DEV int fragidx(int c, int k) {
  int s = k >> 6, kk = k & 63;
  int ch = kk >> 3;            // 0..7 = ks*4 + g
  int ks = ch >> 2, g = ch & 3;
  int j = kk & 7;
  int cg = c >> 5, cc = c & 31;
  int fc = cc >> 4, rl = cc & 15;
  int lane = g * 16 + rl;
  return s * 8192 + cg * 2048 + ks * 1024 + fc * 512 + lane * 8 + j;
}

// ---------------------------------------------------------------------------
// CSR build via 128-row bucket sort (cross-XCD-write-friendly).
// pairs packed: src in bits 0..19, bucket-local dst in bits 20..26.
// ---------------------------------------------------------------------------
__global__ __launch_bounds__(1024) void bucketA(const int* __restrict__ dst,
                                                int* __restrict__ histG,
                                                int E, int chunk, int NB) {
  __shared__ int lh[1024];
  const int t = threadIdx.x;
  for (int i = t; i < NB; i += 1024) lh[i] = 0;
  __syncthreads();
  int s = blockIdx.x * chunk;
  int e = s + chunk; if (e > E) e = E;
  for (int i = s + t; i < e; i += 1024) atomicAdd(&lh[dst[i] >> 7], 1);
  __syncthreads();
  for (int b = t; b < NB; b += 1024) histG[b * NBLK + blockIdx.x] = lh[b];
}

__global__ __launch_bounds__(1024) void bucketS(int* __restrict__ histG,
                                                int* __restrict__ bucketStart,
                                                int NB) {
  __shared__ int btot[1024];
  __shared__ int wsum[16];
  const int t = threadIdx.x, lane = t & 63, wv = t >> 6;
  for (int b = wv; b < NB; b += 16) {
    int carry = 0;
#pragma unroll
    for (int c = 0; c < NBLK / 64; ++c) {
      int idx = b * NBLK + c * 64 + lane;
      int v = histG[idx];
      int x = v;
#pragma unroll
      for (int d = 1; d < 64; d <<= 1) {
        int y = __shfl_up(x, d);
        if (lane >= d) x += y;
      }
      histG[idx] = carry + (x - v);
      carry += __shfl(x, 63);
    }
    if (lane == 0) btot[b] = carry;
  }
  __syncthreads();
  int v = (t < NB) ? btot[t] : 0;
  int x = v;
#pragma unroll
  for (int d = 1; d < 64; d <<= 1) {
    int y = __shfl_up(x, d);
    if (lane >= d) x += y;
  }
  if (lane == 63) wsum[wv] = x;
  __syncthreads();
  if (wv == 0) {
    int y = (lane < 16) ? wsum[lane] : 0;
#pragma unroll
    for (int d = 1; d < 16; d <<= 1) {
      int z = __shfl_up(y, d);
      if (lane >= d) y += z;
    }
    if (lane < 16) wsum[lane] = y;
  }
  __syncthreads();
  int wbase = (wv > 0) ? wsum[wv - 1] : 0;
  int incl = wbase + x;
  if (t < NB) bucketStart[t] = incl - v;
  if (t == NB - 1) bucketStart[NB] = incl;
}

__global__ __launch_bounds__(1024) void bucketB(const int* __restrict__ src,
                                                const int* __restrict__ dstA,
                                                const int* __restrict__ histG,
                                                const int* __restrict__ bucketStart,
                                                unsigned int* __restrict__ pairs,
                                                int E, int chunk, int NB) {
  __shared__ int lbase[1024];
  __shared__ int lcnt[1024];
  const int t = threadIdx.x;
  for (int i = t; i < NB; i += 1024) {
    lbase[i] = bucketStart[i] + histG[i * NBLK + blockIdx.x];
    lcnt[i] = 0;
  }
  __syncthreads();
  int s = blockIdx.x * chunk;
  int e = s + chunk; if (e > E) e = E;
  for (int i = s + t; i < e; i += 1024) {
    int d = dstA[i];
    int b = d >> 7;
    int r = atomicAdd(&lcnt[b], 1);
    pairs[lbase[b] + r] = (unsigned int)src[i] | ((unsigned int)(d & 127) << 20);
  }
}

__global__ __launch_bounds__(256) void bucketC(const unsigned int* __restrict__ pairs,
                                               const int* __restrict__ bucketStart,
                                               int* __restrict__ rowptr,
                                               int* __restrict__ colidx,
                                               float* __restrict__ n1,
                                               float* __restrict__ n2,
                                               int N, int E) {
  __shared__ int degs[128];
  __shared__ int incl[128];
  __shared__ int cur[128];
  const int t = threadIdx.x, lane = t & 63;
  const int b = blockIdx.x;
  const int lo = b << 7;
  const int s0 = bucketStart[b], s1 = bucketStart[b + 1];
  if (t < 128) degs[t] = 0;
  __syncthreads();
  for (int i = s0 + t; i < s1; i += 256) atomicAdd(&degs[pairs[i] >> 20], 1);
  __syncthreads();
  int d = 0, x = 0;
  if (t < 128) {
    d = degs[t];
    x = d;
#pragma unroll
    for (int dd = 1; dd < 64; dd <<= 1) {
      int y = __shfl_up(x, dd);
      if (lane >= dd) x += y;
    }
    incl[t] = x;
  }
  __syncthreads();
  if (t >= 64 && t < 128) incl[t] += incl[63];
  __syncthreads();
  if (t < 128) {
    int excl = incl[t] - d;
    int row = lo + t;
    if (row < N) {
      rowptr[row] = s0 + excl;
      int dd2 = d < 1 ? 1 : d;
      float fd = (float)dd2;
      float r = 1.0f / sqrtf(fd);
      n1[row] = r;
      n2[row] = r / fd;
    }
    cur[t] = excl;
  }
  __syncthreads();
  for (int i = s0 + t; i < s1; i += 256) {
    unsigned int p = pairs[i];
    int off = atomicAdd(&cur[p >> 20], 1);
    colidx[s0 + off] = (int)(p & 0xFFFFFu);
  }
  if (b == 0 && t == 0) rowptr[N] = E;
}

// ---------------------------------------------------------------------------
// agg[i] = bf16( ( sum_e hn[col] ) * n2[i] )   hn = h*n1 (prefolded, bf16)
// 8-wide batched gather, no per-edge scalar loads.
// ---------------------------------------------------------------------------
__global__ __launch_bounds__(256) void agg_kernel(
    const unsigned short* __restrict__ hn, const int* __restrict__ rowptr,
    const int* __restrict__ colidx, const float* __restrict__ n2,
    unsigned short* __restrict__ agg, int N) {
  int wid = (blockIdx.x * 256 + threadIdx.x) >> 6;
  int lane = threadIdx.x & 63;
  if (wid >= N) return;
  int s = rowptr[wid], e = rowptr[wid + 1];
  const unsigned int* h2 = (const unsigned int*)hn;  // 2 bf16 / uint, 64/row
  float ax[4] = {0.f, 0.f, 0.f, 0.f};
  float ay[4] = {0.f, 0.f, 0.f, 0.f};
  for (int i = s; i < e; i += 8) {
    int c[8];
#pragma unroll
    for (int j = 0; j < 8; ++j) {
      int idx = i + j;
      c[j] = colidx[idx < e ? idx : e - 1];
    }
    unsigned int v[8];
#pragma unroll
    for (int j = 0; j < 8; ++j) v[j] = h2[(size_t)c[j] * 64 + lane];
#pragma unroll
    for (int j = 0; j < 8; ++j) {
      bool ok = (i + j) < e;
      ax[j & 3] += ok ? b2f(v[j] & 0xffffu) : 0.f;
      ay[j & 3] += ok ? __uint_as_float(v[j] & 0xffff0000u) : 0.f;
    }
  }
  float m = n2[wid];
  float axs = ((ax[0] + ax[1]) + (ax[2] + ax[3])) * m;
  float ays = ((ay[0] + ay[1]) + (ay[2] + ay[3])) * m;
  ((unsigned int*)agg)[(size_t)wid * 64 + lane] = bf16h(axs) | (bf16h(ays) << 16);
}

// ---------------------------------------------------------------------------
// Weight prep, single launch: transposed + hi/lo split into fragment-major
// images (per-wave coalesced 16B/lane register loads in sage_mm).
// ---------------------------------------------------------------------------
__global__ __launch_bounds__(256) void prep_all(
    const float* __restrict__ encW, const float* __restrict__ W1,
    const float* __restrict__ W2, unsigned short* __restrict__ encWh,
    unsigned short* __restrict__ encWl, unsigned short* __restrict__ W1th,
    unsigned short* __restrict__ W1tl, unsigned short* __restrict__ W2th,
    unsigned short* __restrict__ W2tl, int L) {
  int t = blockIdx.x * 256 + threadIdx.x;
  const int n1e = 16384;
  const int n2e = n1e + L * 32768;
  const int n3e = n2e + L * 16384;
  unsigned int h, l;
  if (t < n1e) {
    int c = t >> 7, k = t & 127;
    split2(encW[k * 128 + c], h, l);
    int di = fragidx(c, k);
    encWh[di] = (unsigned short)h; encWl[di] = (unsigned short)l;
  } else if (t < n2e) {
    int u = t - n1e;
    int ll = u >> 15, w = u & 32767;
    int c = w >> 8, k = w & 255;
    split2(W1[(size_t)ll * 32768 + k * 128 + c], h, l);
    int di = ll * 32768 + fragidx(c, k);
    W1th[di] = (unsigned short)h; W1tl[di] = (unsigned short)l;
  } else if (t < n3e) {
    int u = t - n2e;
    int ll = u >> 14, w = u & 16383;
    int c = w >> 7, k = w & 127;
    split2(W2[(size_t)ll * 16384 + k * 128 + c], h, l);
    int di = ll * 16384 + fragidx(c, k);
    W2th[di] = (unsigned short)h; W2tl[di] = (unsigned short)l;
  }
}

// ---------------------------------------------------------------------------
// Fused MFMA kernel: 256 threads (4 waves), 64-row x 128-col tile, BK=64.
// Double-buffered As (2 x 8KB) with issue-early/write-late staging: per
// phase, next subtile's global loads issue BEFORE the current kloop, and the
// LDS write lands after (latency hides under MFMAs). One barrier per phase.
// W fragments register-loaded from L2-hot fragment-major images (no W LDS).
// KIND 0: h = bf16(fp32A @ W1 + b1). KIND 1: full fused layer (+ hn emit).
// ---------------------------------------------------------------------------
template <int KIND>
__global__ __launch_bounds__(256, 6) void sage_mm(
    const float* __restrict__ Af, const unsigned short* __restrict__ Ab,
    const unsigned short* __restrict__ A2b,
    const unsigned short* __restrict__ W1h, const unsigned short* __restrict__ W1l,
    const unsigned short* __restrict__ W2h, const unsigned short* __restrict__ W2l,
    const float* __restrict__ b1, const float* __restrict__ b2,
    const float* __restrict__ n1f,
    unsigned short* __restrict__ outb, unsigned short* __restrict__ hnout,
    int M) {
  __shared__ unsigned short lds[64 * 128];   // 16KB: buf0|buf1; Cs overlay
  unsigned short* buf0 = lds;
  unsigned short* buf1 = lds + 64 * 64;

  const int t = threadIdx.x;
  const int lane = t & 63;
  const int w = t >> 6;              // 0..3 = col-group
  const int rl = lane & 15, g = lane >> 4;
  const int cbase = w * 32;
  const int rowbase = blockIdx.x * 64;

  // ---- A staging split: load (to regs) / write (to LDS buf) ---------------
  auto loadAb = [&](const unsigned short* __restrict__ src, int k0, int4* v) {
    int r = t >> 2, kc = (t & 3) * 16;
    int grow = rowbase + r;
    const int4* s = (const int4*)(src + (size_t)grow * 128 + k0 + kc);
    v[0] = (grow < M) ? s[0] : make_int4(0, 0, 0, 0);
    v[1] = (grow < M) ? s[1] : make_int4(0, 0, 0, 0);
  };
  auto writeAb = [&](unsigned short* dst, const int4* v) {
    int r = t >> 2, kc = (t & 3) * 16;
#pragma unroll
    for (int j = 0; j < 2; ++j) {
      int ch = (kc >> 3) + j;
      int off = r * 64 * 2 + ((ch ^ (r & 7)) << 4);
      *(int4*)((char*)dst + off) = v[j];
    }
  };
  auto loadAf = [&](const float* __restrict__ src, int k0, float4* v) {
    int r = t >> 2, kc = (t & 3) * 16;
    int grow = rowbase + r;
    const float4* s = (const float4*)(src + (size_t)grow * 128 + k0 + kc);
#pragma unroll
    for (int j = 0; j < 4; ++j)
      v[j] = (grow < M) ? s[j] : make_float4(0.f, 0.f, 0.f, 0.f);
  };
  auto writeAf = [&](unsigned short* dst, const float4* v) {
    int r = t >> 2, kc = (t & 3) * 16;
#pragma unroll
    for (int j = 0; j < 4; ++j) {
      unsigned int h0 = bf16h(v[j].x), h1 = bf16h(v[j].y);
      unsigned int h2 = bf16h(v[j].z), h3 = bf16h(v[j].w);
      int k = kc + j * 4;
      int off = r * 128 + (((k >> 3) ^ (r & 7)) << 4) + (k & 7) * 2;
      *(int2*)((char*)dst + off) =
          make_int2((int)(h0 | (h1 << 16)), (int)(h2 | (h3 << 16)));
    }
  };

  f32x4 acc[4][2];
  auto zacc = [&]() {
#pragma unroll
    for (int i = 0; i < 4; ++i)
#pragma unroll
      for (int j = 0; j < 2; ++j) {
        f32x4 z = {0.f, 0.f, 0.f, 0.f};
        acc[i][j] = z;
      }
  };

  // kloop over one staged A-subtile in `as`; W fragments from global (L2-hot)
  auto kloop = [&](const unsigned short* imgh, const unsigned short* imgl,
                   int sub, const unsigned short* as) {
    const unsigned short* bh0 = imgh + sub * 8192 + w * 2048 + lane * 8;
    const unsigned short* bl0 = imgl + sub * 8192 + w * 2048 + lane * 8;
#pragma unroll
    for (int ks = 0; ks < 2; ++ks) {
      short8 aH[4], bH[2], bL[2];
#pragma unroll
      for (int fc = 0; fc < 2; ++fc) {
        bH[fc] = *(const short8*)(bh0 + ks * 1024 + fc * 512);
        bL[fc] = *(const short8*)(bl0 + ks * 1024 + fc * 512);
      }
#pragma unroll
      for (int fr = 0; fr < 4; ++fr) {
        int row = fr * 16 + rl;
        int off = row * 128 + (((ks * 4 + g) ^ (row & 7)) << 4);
        aH[fr] = *(const short8*)((const char*)as + off);
      }
#pragma unroll
      for (int fr = 0; fr < 4; ++fr)
#pragma unroll
        for (int fc = 0; fc < 2; ++fc) {
          acc[fr][fc] = __builtin_amdgcn_mfma_f32_16x16x32_bf16(
              aH[fr], bH[fc], acc[fr][fc], 0, 0, 0);
          acc[fr][fc] = __builtin_amdgcn_mfma_f32_16x16x32_bf16(
              aH[fr], bL[fc], acc[fr][fc], 0, 0, 0);
        }
    }
  };

  // z = relu(a + b1) staged (bf16) into `dst` for cols [c0,c0+64)
  auto zstage = [&](int c0, const f32x4 (&a)[4][2], unsigned short* dst) {
#pragma unroll
    for (int fc = 0; fc < 2; ++fc) {
      int col = cbase + fc * 16 + rl;
      unsigned int lc = (unsigned int)(col - c0);
      if (lc < 64u) {
        float bb = b1[col];
#pragma unroll
        for (int fr = 0; fr < 4; ++fr)
#pragma unroll
          for (int q = 0; q < 4; ++q) {
            int row = fr * 16 + g * 4 + q;
            float z = fmaxf(a[fr][fc][q] + bb, 0.f);
            int off = row * 128 + (((lc >> 3) ^ (row & 7)) << 4) + (lc & 7) * 2;
            *(unsigned short*)((char*)dst + off) = (unsigned short)bf16h(z);
          }
      }
    }
  };

  zacc();
  if (KIND == 0) {
    float4 vf[4];
    loadAf(Af, 0, vf); writeAf(buf0, vf);
    __syncthreads();
    loadAf(Af, 64, vf);                 // issue early
    kloop(W1h, W1l, 0, buf0);           // compute under load latency
    writeAf(buf1, vf);                  // write late
    __syncthreads();
    kloop(W1h, W1l, 1, buf1);
  } else {
    int4 va[2];
    loadAb(Ab, 0, va); writeAb(buf0, va);
    __syncthreads();
    loadAb(Ab, 64, va);
    kloop(W1h, W1l, 0, buf0);
    writeAb(buf1, va);
    __syncthreads();
    loadAb(A2b, 0, va);
    kloop(W1h, W1l, 1, buf1);
    writeAb(buf0, va);
    __syncthreads();
    loadAb(A2b, 64, va);
    kloop(W1h, W1l, 2, buf0);
    writeAb(buf1, va);
    __syncthreads();
    kloop(W1h, W1l, 3, buf1);           // GEMM1 complete in acc

    f32x4 acc1[4][2];
#pragma unroll
    for (int i = 0; i < 4; ++i)
#pragma unroll
      for (int j = 0; j < 2; ++j) acc1[i][j] = acc[i][j];
    zacc();
    zstage(0, acc1, buf0);              // buf0 free (last read P2); in-wave ok
    __syncthreads();
    zstage(64, acc1, buf1);             // buf1 reads all done (barrier above)
    kloop(W2h, W2l, 0, buf0);           // concurrent: reads buf0
    __syncthreads();
    kloop(W2h, W2l, 1, buf1);
  }

  // ---- epilogue: stage C in LDS (16KB overlay) -> coalesced writes ---------
  __syncthreads();
  unsigned short* Cs = lds;
  const float* bias = (KIND == 0) ? b1 : b2;
#pragma unroll
  for (int fc = 0; fc < 2; ++fc) {
    int col = cbase + fc * 16 + rl;
    float bb = bias[col];
#pragma unroll
    for (int fr = 0; fr < 4; ++fr)
#pragma unroll
      for (int q = 0; q < 4; ++q) {
        int row = fr * 16 + g * 4 + q;
        float val = acc[fr][fc][q] + bb;
        if (KIND == 1) val = fmaxf(val, 0.f);
        Cs[row * 128 + col] = (unsigned short)bf16h(val);
      }
  }
  __syncthreads();
#pragma unroll
  for (int p = 0; p < 4; ++p) {
    int bo = p * 4096 + t * 16;
    int row = bo >> 8;
    int grow = rowbase + row;
    if (grow >= M) continue;
    int4 z4 = *(const int4*)((const char*)Cs + bo);
    int* zp = (int*)&z4;
    if (KIND == 1) {
      int4 a4 = *(const int4*)((const char*)Ab + (size_t)grow * 256 + (bo & 255));
      const int* ap = (const int*)&a4;
#pragma unroll
      for (int u = 0; u < 4; ++u) {
        unsigned int za = (unsigned int)zp[u], aa = (unsigned int)ap[u];
        float vlo = b2f(za & 0xffffu) + b2f(aa & 0xffffu);
        float vhi = __uint_as_float(za & 0xffff0000u) +
                    __uint_as_float(aa & 0xffff0000u);
        zp[u] = (int)(bf16h(vlo) | (bf16h(vhi) << 16));
      }
    }
    *(int4*)((char*)outb + (size_t)grow * 256 + (bo & 255)) = z4;
    if (hnout) {  // hn = bf16(h * n1[grow]); skipped on last layer
      float n1r = n1f[grow];
      int4 hn4;
      int* hp = (int*)&hn4;
#pragma unroll
      for (int u = 0; u < 4; ++u) {
        unsigned int za = (unsigned int)zp[u];
        float vlo = b2f(za & 0xffffu) * n1r;
        float vhi = __uint_as_float(za & 0xffff0000u) * n1r;
        hp[u] = (int)(bf16h(vlo) | (bf16h(vhi) << 16));
      }
      *(int4*)((char*)hnout + (size_t)grow * 256 + (bo & 255)) = hn4;
    }
  }
}

// ---------------------------------------------------------------------------
// Pooling + readout (h in bf16)
// ---------------------------------------------------------------------------
__global__ __launch_bounds__(256) void pool_partial(
    const unsigned short* __restrict__ h, float* __restrict__ partial, int N) {
  int col = threadIdx.x & 127;
  int stream = blockIdx.x * 2 + (threadIdx.x >> 7);
  float s = 0.f;
  for (int r = stream; r < N; r += 512)
    s += b2f((unsigned int)h[(size_t)r * 128 + col]);
  partial[stream * 128 + col] = s;
}

__global__ __launch_bounds__(256) void readout_kernel(
    const float* __restrict__ partial, const float* __restrict__ rW1,
    const float* __restrict__ rb1, const float* __restrict__ rW2,
    const float* __restrict__ rb2, const float* __restrict__ rW3,
    const float* __restrict__ rb3, float* __restrict__ outp, int N) {
  __shared__ float pooled[128];
  __shared__ float x1[64];
  __shared__ float x2[32];
  int t = threadIdx.x;
  if (t < 128) {
    float s = 0.f;
    for (int i = 0; i < 512; ++i) s += partial[i * 128 + t];
    pooled[t] = s / (float)N;
  }
  __syncthreads();
  if (t < 64) {
    float s = rb1[t];
    for (int k = 0; k < 128; ++k) s = fmaf(pooled[k], rW1[k * 64 + t], s);
    x1[t] = fmaxf(s, 0.f);
  }
  __syncthreads();
  if (t < 32) {
    float s = rb2[t];
    for (int k = 0; k < 64; ++k) s = fmaf(x1[k], rW2[k * 32 + t], s);
    x2[t] = fmaxf(s, 0.f);
  }
  __syncthreads();
  if (t < 10) {
    float s = rb3[t];
    for (int k = 0; k < 32; ++k) s = fmaf(x2[k], rW3[k * 10 + t], s);
    outp[t] = s;
  }
}

extern "C" void kernel_launch(void* const* d_in, const int* in_sizes, int n_in,
                              void* d_out, int out_size, void* d_ws, size_t ws_size,
                              hipStream_t stream) {
  const float* h_in  = (const float*)d_in[0];
  const int*   src   = (const int*)d_in[1];
  const int*   dst   = (const int*)d_in[2];
  const float* enc_W = (const float*)d_in[3];
  const float* enc_b = (const float*)d_in[4];
  const float* W1    = (const float*)d_in[5];
  const float* b1    = (const float*)d_in[6];
  const float* W2    = (const float*)d_in[7];
  const float* b2    = (const float*)d_in[8];
  const float* rW1   = (const float*)d_in[9];
  const float* rb1   = (const float*)d_in[10];
  const float* rW2   = (const float*)d_in[11];
  const float* rb2   = (const float*)d_in[12];
  const float* rW3   = (const float*)d_in[13];
  const float* rb3   = (const float*)d_in[14];

  const int N = in_sizes[0] / 128;
  const int E = in_sizes[1];
  const int L = in_sizes[6] / 128;
  const int NB = (N + 127) >> 7;
  const int chunk = (E + NBLK - 1) / NBLK;

  char* ws = (char*)d_ws;
  size_t off = 0;
  auto alloc = [&](size_t bytes) {
    char* p = ws + off;
    off = (off + bytes + 511) & ~(size_t)511;
    return p;
  };
  unsigned short* h   = (unsigned short*)alloc((size_t)N * 128 * 2);
  unsigned short* hn  = (unsigned short*)alloc((size_t)N * 128 * 2);
  unsigned short* agg = (unsigned short*)alloc((size_t)N * 128 * 2);
  int* rowptr     = (int*)alloc((size_t)(N + 1) * 4);
  int* colidx     = (int*)alloc((size_t)E * 4);
  float* n1       = (float*)alloc((size_t)N * 4);
  float* n2       = (float*)alloc((size_t)N * 4);
  int* histG      = (int*)alloc((size_t)NB * NBLK * 4);
  int* bucketStart= (int*)alloc((size_t)(NB + 1) * 4);
  float* partial  = (float*)alloc((size_t)512 * 128 * 4);
  unsigned short* encWh = (unsigned short*)alloc(16384 * 2);
  unsigned short* encWl = (unsigned short*)alloc(16384 * 2);
  unsigned short* W1th  = (unsigned short*)alloc((size_t)L * 32768 * 2);
  unsigned short* W1tl  = (unsigned short*)alloc((size_t)L * 32768 * 2);
  unsigned short* W2th  = (unsigned short*)alloc((size_t)L * 16384 * 2);
  unsigned short* W2tl  = (unsigned short*)alloc((size_t)L * 16384 * 2);
  unsigned int* pairs = (unsigned int*)alloc((size_t)E * 4);  // CSR scratch
  (void)ws_size; (void)n_in; (void)out_size;

  {
    int tot = 16384 + L * 32768 + L * 16384;
    prep_all<<<(tot + 255) / 256, 256, 0, stream>>>(
        enc_W, W1, W2, encWh, encWl, W1th, W1tl, W2th, W2tl, L);
  }

  bucketA<<<NBLK, 1024, 0, stream>>>(dst, histG, E, chunk, NB);
  bucketS<<<1, 1024, 0, stream>>>(histG, bucketStart, NB);
  bucketB<<<NBLK, 1024, 0, stream>>>(src, dst, histG, bucketStart, pairs, E,
                                     chunk, NB);
  bucketC<<<NB, 256, 0, stream>>>(pairs, bucketStart, rowptr, colidx, n1, n2, N, E);

  const int gblocks = (N + 63) / 64;
  sage_mm<0><<<gblocks, 256, 0, stream>>>(h_in, nullptr, nullptr, encWh, encWl,
                                          nullptr, nullptr, enc_b, nullptr,
                                          n1, h, hn, N);
  for (int l = 0; l < L; ++l) {
    agg_kernel<<<(N + 3) / 4, 256, 0, stream>>>(hn, rowptr, colidx, n2, agg, N);
    sage_mm<1><<<gblocks, 256, 0, stream>>>(
        nullptr, h, agg, W1th + (size_t)l * 32768, W1tl + (size_t)l * 32768,
        W2th + (size_t)l * 16384, W2tl + (size_t)l * 16384,
        b1 + l * 128, b2 + l * 128, n1, h,
        (l == L - 1) ? nullptr : hn, N);
  }
  pool_partial<<<256, 256, 0, stream>>>(h, partial, N);
  readout_kernel<<<1, 256, 0, stream>>>(partial, rW1, rb1, rW2, rb2, rW3, rb3,
                                        (float*)d_out, N);
}

// Round 23
// 576.076 us; speedup vs baseline: 1.2989x; 1.1313x over previous
//
#include <hip/hip_runtime.h>
#include <math.h>

typedef short short8 __attribute__((ext_vector_type(8)));
typedef float f32x4 __attribute__((ext_vector_type(4)));

#define DEV static __device__ __forceinline__
#define NBLK 256   // blocks for bucket passes A/B

// ---- fp32 -> bf16 round-to-nearest-even; and hi/lo split -------------------
DEV unsigned int bf16h(float x) {
  unsigned int u = __float_as_uint(x);
  return (u + 0x7FFFu + ((u >> 16) & 1u)) >> 16;
}
DEV void split2(float x, unsigned int& h, unsigned int& l) {
  h = bf16h(x);
  float hf = __uint_as_float(h << 16);
  l = bf16h(x - hf);
}
DEV float b2f(unsigned int u) { return __uint_as_float(u << 16); }

// fragment-major W image index (ushort units) for element (c,k) of a
// [C=128 cols][K] transposed weight. Per 64-k subtile s (8192 shorts):
// [cg 0..3][ks 0..1][fc 0..1][lane 0..63][j 0..7] where
// col = cg*32 + fc*16 + (lane&15), k = s*64 + (ks*4 + (lane>>4))*8 + j.
DEV int fragidx(int c, int k) {
  int s = k >> 6, kk = k & 63;
  int ch = kk >> 3;            // 0..7 = ks*4 + g
  int ks = ch >> 2, g = ch & 3;
  int j = kk & 7;
  int cg = c >> 5, cc = c & 31;
  int fc = cc >> 4, rl = cc & 15;
  int lane = g * 16 + rl;
  return s * 8192 + cg * 2048 + ks * 1024 + fc * 512 + lane * 8 + j;
}

// ---------------------------------------------------------------------------
// CSR build via 128-row bucket sort (cross-XCD-write-friendly).
// pairs packed: src in bits 0..19, bucket-local dst in bits 20..26.
// ---------------------------------------------------------------------------
__global__ __launch_bounds__(1024) void bucketA(const int* __restrict__ dst,
                                                int* __restrict__ histG,
                                                int E, int chunk, int NB) {
  __shared__ int lh[1024];
  const int t = threadIdx.x;
  for (int i = t; i < NB; i += 1024) lh[i] = 0;
  __syncthreads();
  int s = blockIdx.x * chunk;
  int e = s + chunk; if (e > E) e = E;
  for (int i = s + t; i < e; i += 1024) atomicAdd(&lh[dst[i] >> 7], 1);
  __syncthreads();
  for (int b = t; b < NB; b += 1024) histG[b * NBLK + blockIdx.x] = lh[b];
}

__global__ __launch_bounds__(1024) void bucketS(int* __restrict__ histG,
                                                int* __restrict__ bucketStart,
                                                int NB) {
  __shared__ int btot[1024];
  __shared__ int wsum[16];
  const int t = threadIdx.x, lane = t & 63, wv = t >> 6;
  for (int b = wv; b < NB; b += 16) {
    int carry = 0;
#pragma unroll
    for (int c = 0; c < NBLK / 64; ++c) {
      int idx = b * NBLK + c * 64 + lane;
      int v = histG[idx];
      int x = v;
#pragma unroll
      for (int d = 1; d < 64; d <<= 1) {
        int y = __shfl_up(x, d);
        if (lane >= d) x += y;
      }
      histG[idx] = carry + (x - v);
      carry += __shfl(x, 63);
    }
    if (lane == 0) btot[b] = carry;
  }
  __syncthreads();
  int v = (t < NB) ? btot[t] : 0;
  int x = v;
#pragma unroll
  for (int d = 1; d < 64; d <<= 1) {
    int y = __shfl_up(x, d);
    if (lane >= d) x += y;
  }
  if (lane == 63) wsum[wv] = x;
  __syncthreads();
  if (wv == 0) {
    int y = (lane < 16) ? wsum[lane] : 0;
#pragma unroll
    for (int d = 1; d < 16; d <<= 1) {
      int z = __shfl_up(y, d);
      if (lane >= d) y += z;
    }
    if (lane < 16) wsum[lane] = y;
  }
  __syncthreads();
  int wbase = (wv > 0) ? wsum[wv - 1] : 0;
  int incl = wbase + x;
  if (t < NB) bucketStart[t] = incl - v;
  if (t == NB - 1) bucketStart[NB] = incl;
}

__global__ __launch_bounds__(1024) void bucketB(const int* __restrict__ src,
                                                const int* __restrict__ dstA,
                                                const int* __restrict__ histG,
                                                const int* __restrict__ bucketStart,
                                                unsigned int* __restrict__ pairs,
                                                int E, int chunk, int NB) {
  __shared__ int lbase[1024];
  __shared__ int lcnt[1024];
  const int t = threadIdx.x;
  for (int i = t; i < NB; i += 1024) {
    lbase[i] = bucketStart[i] + histG[i * NBLK + blockIdx.x];
    lcnt[i] = 0;
  }
  __syncthreads();
  int s = blockIdx.x * chunk;
  int e = s + chunk; if (e > E) e = E;
  for (int i = s + t; i < e; i += 1024) {
    int d = dstA[i];
    int b = d >> 7;
    int r = atomicAdd(&lcnt[b], 1);
    pairs[lbase[b] + r] = (unsigned int)src[i] | ((unsigned int)(d & 127) << 20);
  }
}

__global__ __launch_bounds__(256) void bucketC(const unsigned int* __restrict__ pairs,
                                               const int* __restrict__ bucketStart,
                                               int* __restrict__ rowptr,
                                               int* __restrict__ colidx,
                                               float* __restrict__ n1,
                                               float* __restrict__ n2,
                                               int N, int E) {
  __shared__ int degs[128];
  __shared__ int incl[128];
  __shared__ int cur[128];
  const int t = threadIdx.x, lane = t & 63;
  const int b = blockIdx.x;
  const int lo = b << 7;
  const int s0 = bucketStart[b], s1 = bucketStart[b + 1];
  if (t < 128) degs[t] = 0;
  __syncthreads();
  for (int i = s0 + t; i < s1; i += 256) atomicAdd(&degs[pairs[i] >> 20], 1);
  __syncthreads();
  int d = 0, x = 0;
  if (t < 128) {
    d = degs[t];
    x = d;
#pragma unroll
    for (int dd = 1; dd < 64; dd <<= 1) {
      int y = __shfl_up(x, dd);
      if (lane >= dd) x += y;
    }
    incl[t] = x;
  }
  __syncthreads();
  if (t >= 64 && t < 128) incl[t] += incl[63];
  __syncthreads();
  if (t < 128) {
    int excl = incl[t] - d;
    int row = lo + t;
    if (row < N) {
      rowptr[row] = s0 + excl;
      int dd2 = d < 1 ? 1 : d;
      float fd = (float)dd2;
      float r = 1.0f / sqrtf(fd);
      n1[row] = r;
      n2[row] = r / fd;
    }
    cur[t] = excl;
  }
  __syncthreads();
  for (int i = s0 + t; i < s1; i += 256) {
    unsigned int p = pairs[i];
    int off = atomicAdd(&cur[p >> 20], 1);
    colidx[s0 + off] = (int)(p & 0xFFFFFu);
  }
  if (b == 0 && t == 0) rowptr[N] = E;
}

// ---------------------------------------------------------------------------
// agg[i] = bf16( ( sum_e hn[col] ) * n2[i] )   hn = h*n1 (prefolded, bf16)
// 8-wide batched gather, no per-edge scalar loads.
// ---------------------------------------------------------------------------
__global__ __launch_bounds__(256) void agg_kernel(
    const unsigned short* __restrict__ hn, const int* __restrict__ rowptr,
    const int* __restrict__ colidx, const float* __restrict__ n2,
    unsigned short* __restrict__ agg, int N) {
  int wid = (blockIdx.x * 256 + threadIdx.x) >> 6;
  int lane = threadIdx.x & 63;
  if (wid >= N) return;
  int s = rowptr[wid], e = rowptr[wid + 1];
  const unsigned int* h2 = (const unsigned int*)hn;  // 2 bf16 / uint, 64/row
  float ax[4] = {0.f, 0.f, 0.f, 0.f};
  float ay[4] = {0.f, 0.f, 0.f, 0.f};
  for (int i = s; i < e; i += 8) {
    int c[8];
#pragma unroll
    for (int j = 0; j < 8; ++j) {
      int idx = i + j;
      c[j] = colidx[idx < e ? idx : e - 1];
    }
    unsigned int v[8];
#pragma unroll
    for (int j = 0; j < 8; ++j) v[j] = h2[(size_t)c[j] * 64 + lane];
#pragma unroll
    for (int j = 0; j < 8; ++j) {
      bool ok = (i + j) < e;
      ax[j & 3] += ok ? b2f(v[j] & 0xffffu) : 0.f;
      ay[j & 3] += ok ? __uint_as_float(v[j] & 0xffff0000u) : 0.f;
    }
  }
  float m = n2[wid];
  float axs = ((ax[0] + ax[1]) + (ax[2] + ax[3])) * m;
  float ays = ((ay[0] + ay[1]) + (ay[2] + ay[3])) * m;
  ((unsigned int*)agg)[(size_t)wid * 64 + lane] = bf16h(axs) | (bf16h(ays) << 16);
}

// ---------------------------------------------------------------------------
// Weight prep, single launch: transposed + hi/lo split into fragment-major
// images (per-wave coalesced 16B/lane register loads in sage_mm).
// ---------------------------------------------------------------------------
__global__ __launch_bounds__(256) void prep_all(
    const float* __restrict__ encW, const float* __restrict__ W1,
    const float* __restrict__ W2, unsigned short* __restrict__ encWh,
    unsigned short* __restrict__ encWl, unsigned short* __restrict__ W1th,
    unsigned short* __restrict__ W1tl, unsigned short* __restrict__ W2th,
    unsigned short* __restrict__ W2tl, int L) {
  int t = blockIdx.x * 256 + threadIdx.x;
  const int n1e = 16384;
  const int n2e = n1e + L * 32768;
  const int n3e = n2e + L * 16384;
  unsigned int h, l;
  if (t < n1e) {
    int c = t >> 7, k = t & 127;
    split2(encW[k * 128 + c], h, l);
    int di = fragidx(c, k);
    encWh[di] = (unsigned short)h; encWl[di] = (unsigned short)l;
  } else if (t < n2e) {
    int u = t - n1e;
    int ll = u >> 15, w = u & 32767;
    int c = w >> 8, k = w & 255;
    split2(W1[(size_t)ll * 32768 + k * 128 + c], h, l);
    int di = ll * 32768 + fragidx(c, k);
    W1th[di] = (unsigned short)h; W1tl[di] = (unsigned short)l;
  } else if (t < n3e) {
    int u = t - n2e;
    int ll = u >> 14, w = u & 16383;
    int c = w >> 7, k = w & 127;
    split2(W2[(size_t)ll * 16384 + k * 128 + c], h, l);
    int di = ll * 16384 + fragidx(c, k);
    W2th[di] = (unsigned short)h; W2tl[di] = (unsigned short)l;
  }
}

// ---------------------------------------------------------------------------
// Fused MFMA kernel: 256 threads (4 waves), 64-row x 128-col tile, BK=64.
// Double-buffered As (2 x 8KB), issue-early/write-late staging; W fragments
// register-loaded from L2-hot fragment-major images (no W LDS).
// KIND 0: h = bf16(fp32A @ W1 + b1). KIND 1: full fused layer (+ hn emit).
// Last layer (gpart != nullptr): no h/hn writes; per-block column sums of
// the residual output are LDS-reduced and atomically added into
// gpart[(blockIdx&15)*128 + col] (graph-pooling fusion).
// ---------------------------------------------------------------------------
template <int KIND>
__global__ __launch_bounds__(256, 6) void sage_mm(
    const float* __restrict__ Af, const unsigned short* __restrict__ Ab,
    const unsigned short* __restrict__ A2b,
    const unsigned short* __restrict__ W1h, const unsigned short* __restrict__ W1l,
    const unsigned short* __restrict__ W2h, const unsigned short* __restrict__ W2l,
    const float* __restrict__ b1, const float* __restrict__ b2,
    const float* __restrict__ n1f,
    unsigned short* __restrict__ outb, unsigned short* __restrict__ hnout,
    float* __restrict__ gpart, int M) {
  __shared__ unsigned short lds[64 * 128];   // 16KB: buf0|buf1; Cs overlay
  unsigned short* buf0 = lds;
  unsigned short* buf1 = lds + 64 * 64;

  const int t = threadIdx.x;
  const int lane = t & 63;
  const int w = t >> 6;              // 0..3 = col-group
  const int rl = lane & 15, g = lane >> 4;
  const int cbase = w * 32;
  const int rowbase = blockIdx.x * 64;

  // ---- A staging split: load (to regs) / write (to LDS buf) ---------------
  auto loadAb = [&](const unsigned short* __restrict__ src, int k0, int4* v) {
    int r = t >> 2, kc = (t & 3) * 16;
    int grow = rowbase + r;
    const int4* s = (const int4*)(src + (size_t)grow * 128 + k0 + kc);
    v[0] = (grow < M) ? s[0] : make_int4(0, 0, 0, 0);
    v[1] = (grow < M) ? s[1] : make_int4(0, 0, 0, 0);
  };
  auto writeAb = [&](unsigned short* dst, const int4* v) {
    int r = t >> 2, kc = (t & 3) * 16;
#pragma unroll
    for (int j = 0; j < 2; ++j) {
      int ch = (kc >> 3) + j;
      int off = r * 64 * 2 + ((ch ^ (r & 7)) << 4);
      *(int4*)((char*)dst + off) = v[j];
    }
  };
  auto loadAf = [&](const float* __restrict__ src, int k0, float4* v) {
    int r = t >> 2, kc = (t & 3) * 16;
    int grow = rowbase + r;
    const float4* s = (const float4*)(src + (size_t)grow * 128 + k0 + kc);
#pragma unroll
    for (int j = 0; j < 4; ++j)
      v[j] = (grow < M) ? s[j] : make_float4(0.f, 0.f, 0.f, 0.f);
  };
  auto writeAf = [&](unsigned short* dst, const float4* v) {
    int r = t >> 2, kc = (t & 3) * 16;
#pragma unroll
    for (int j = 0; j < 4; ++j) {
      unsigned int h0 = bf16h(v[j].x), h1 = bf16h(v[j].y);
      unsigned int h2 = bf16h(v[j].z), h3 = bf16h(v[j].w);
      int k = kc + j * 4;
      int off = r * 128 + (((k >> 3) ^ (r & 7)) << 4) + (k & 7) * 2;
      *(int2*)((char*)dst + off) =
          make_int2((int)(h0 | (h1 << 16)), (int)(h2 | (h3 << 16)));
    }
  };

  f32x4 acc[4][2];
  auto zacc = [&]() {
#pragma unroll
    for (int i = 0; i < 4; ++i)
#pragma unroll
      for (int j = 0; j < 2; ++j) {
        f32x4 z = {0.f, 0.f, 0.f, 0.f};
        acc[i][j] = z;
      }
  };

  // kloop over one staged A-subtile in `as`; W fragments from global (L2-hot)
  auto kloop = [&](const unsigned short* imgh, const unsigned short* imgl,
                   int sub, const unsigned short* as) {
    const unsigned short* bh0 = imgh + sub * 8192 + w * 2048 + lane * 8;
    const unsigned short* bl0 = imgl + sub * 8192 + w * 2048 + lane * 8;
#pragma unroll
    for (int ks = 0; ks < 2; ++ks) {
      short8 aH[4], bH[2], bL[2];
#pragma unroll
      for (int fc = 0; fc < 2; ++fc) {
        bH[fc] = *(const short8*)(bh0 + ks * 1024 + fc * 512);
        bL[fc] = *(const short8*)(bl0 + ks * 1024 + fc * 512);
      }
#pragma unroll
      for (int fr = 0; fr < 4; ++fr) {
        int row = fr * 16 + rl;
        int off = row * 128 + (((ks * 4 + g) ^ (row & 7)) << 4);
        aH[fr] = *(const short8*)((const char*)as + off);
      }
#pragma unroll
      for (int fr = 0; fr < 4; ++fr)
#pragma unroll
        for (int fc = 0; fc < 2; ++fc) {
          acc[fr][fc] = __builtin_amdgcn_mfma_f32_16x16x32_bf16(
              aH[fr], bH[fc], acc[fr][fc], 0, 0, 0);
          acc[fr][fc] = __builtin_amdgcn_mfma_f32_16x16x32_bf16(
              aH[fr], bL[fc], acc[fr][fc], 0, 0, 0);
        }
    }
  };

  // z = relu(a + b1) staged (bf16) into `dst` for cols [c0,c0+64)
  auto zstage = [&](int c0, const f32x4 (&a)[4][2], unsigned short* dst) {
#pragma unroll
    for (int fc = 0; fc < 2; ++fc) {
      int col = cbase + fc * 16 + rl;
      unsigned int lc = (unsigned int)(col - c0);
      if (lc < 64u) {
        float bb = b1[col];
#pragma unroll
        for (int fr = 0; fr < 4; ++fr)
#pragma unroll
          for (int q = 0; q < 4; ++q) {
            int row = fr * 16 + g * 4 + q;
            float z = fmaxf(a[fr][fc][q] + bb, 0.f);
            int off = row * 128 + (((lc >> 3) ^ (row & 7)) << 4) + (lc & 7) * 2;
            *(unsigned short*)((char*)dst + off) = (unsigned short)bf16h(z);
          }
      }
    }
  };

  zacc();
  if (KIND == 0) {
    float4 vf[4];
    loadAf(Af, 0, vf); writeAf(buf0, vf);
    __syncthreads();
    loadAf(Af, 64, vf);                 // issue early
    kloop(W1h, W1l, 0, buf0);           // compute under load latency
    writeAf(buf1, vf);                  // write late
    __syncthreads();
    kloop(W1h, W1l, 1, buf1);
  } else {
    int4 va[2];
    loadAb(Ab, 0, va); writeAb(buf0, va);
    __syncthreads();
    loadAb(Ab, 64, va);
    kloop(W1h, W1l, 0, buf0);
    writeAb(buf1, va);
    __syncthreads();
    loadAb(A2b, 0, va);
    kloop(W1h, W1l, 1, buf1);
    writeAb(buf0, va);
    __syncthreads();
    loadAb(A2b, 64, va);
    kloop(W1h, W1l, 2, buf0);
    writeAb(buf1, va);
    __syncthreads();
    kloop(W1h, W1l, 3, buf1);           // GEMM1 complete in acc

    f32x4 acc1[4][2];
#pragma unroll
    for (int i = 0; i < 4; ++i)
#pragma unroll
      for (int j = 0; j < 2; ++j) acc1[i][j] = acc[i][j];
    zacc();
    zstage(0, acc1, buf0);              // buf0 free (last read P2); in-wave ok
    __syncthreads();
    zstage(64, acc1, buf1);             // buf1 reads all done (barrier above)
    kloop(W2h, W2l, 0, buf0);           // concurrent: reads buf0
    __syncthreads();
    kloop(W2h, W2l, 1, buf1);
  }

  // ---- epilogue: stage C in LDS (16KB overlay) -> coalesced writes ---------
  __syncthreads();
  unsigned short* Cs = lds;
  const float* bias = (KIND == 0) ? b1 : b2;
#pragma unroll
  for (int fc = 0; fc < 2; ++fc) {
    int col = cbase + fc * 16 + rl;
    float bb = bias[col];
#pragma unroll
    for (int fr = 0; fr < 4; ++fr)
#pragma unroll
      for (int q = 0; q < 4; ++q) {
        int row = fr * 16 + g * 4 + q;
        float val = acc[fr][fc][q] + bb;
        if (KIND == 1) val = fmaxf(val, 0.f);
        Cs[row * 128 + col] = (unsigned short)bf16h(val);
      }
  }
  __syncthreads();
  float colsum[8];
#pragma unroll
  for (int j = 0; j < 8; ++j) colsum[j] = 0.f;
#pragma unroll
  for (int p = 0; p < 4; ++p) {
    int bo = p * 4096 + t * 16;
    int row = bo >> 8;
    int grow = rowbase + row;
    if (grow >= M) continue;
    int4 z4 = *(const int4*)((const char*)Cs + bo);
    int* zp = (int*)&z4;
    if (KIND == 1) {
      int4 a4 = *(const int4*)((const char*)Ab + (size_t)grow * 256 + (bo & 255));
      const int* ap = (const int*)&a4;
#pragma unroll
      for (int u = 0; u < 4; ++u) {
        unsigned int za = (unsigned int)zp[u], aa = (unsigned int)ap[u];
        float vlo = b2f(za & 0xffffu) + b2f(aa & 0xffffu);
        float vhi = __uint_as_float(za & 0xffff0000u) +
                    __uint_as_float(aa & 0xffff0000u);
        zp[u] = (int)(bf16h(vlo) | (bf16h(vhi) << 16));
      }
    }
    if (KIND == 1 && gpart) {
      // pooling fusion: accumulate column sums; no global writes
#pragma unroll
      for (int u = 0; u < 4; ++u) {
        unsigned int za = (unsigned int)zp[u];
        colsum[u * 2] += b2f(za & 0xffffu);
        colsum[u * 2 + 1] += __uint_as_float(za & 0xffff0000u);
      }
      continue;
    }
    *(int4*)((char*)outb + (size_t)grow * 256 + (bo & 255)) = z4;
    if (KIND == 1 && hnout) {  // hn = bf16(h * n1[grow])
      float n1r = n1f[grow];
      int4 hn4;
      int* hp = (int*)&hn4;
#pragma unroll
      for (int u = 0; u < 4; ++u) {
        unsigned int za = (unsigned int)zp[u];
        float vlo = b2f(za & 0xffffu) * n1r;
        float vhi = __uint_as_float(za & 0xffff0000u) * n1r;
        hp[u] = (int)(bf16h(vlo) | (bf16h(vhi) << 16));
      }
      *(int4*)((char*)hnout + (size_t)grow * 256 + (bo & 255)) = hn4;
    } else if (KIND == 0) {
      float n1r = n1f[grow];
      int4 hn4;
      int* hp = (int*)&hn4;
#pragma unroll
      for (int u = 0; u < 4; ++u) {
        unsigned int za = (unsigned int)zp[u];
        float vlo = b2f(za & 0xffffu) * n1r;
        float vhi = __uint_as_float(za & 0xffff0000u) * n1r;
        hp[u] = (int)(bf16h(vlo) | (bf16h(vhi) << 16));
      }
      *(int4*)((char*)hnout + (size_t)grow * 256 + (bo & 255)) = hn4;
    }
  }
  if (KIND == 1 && gpart) {
    // LDS reduce 16 row-groups -> 128 col sums -> scattered atomicAdd
    __syncthreads();
    float* lfs = (float*)lds;          // 256 threads x 8 floats = 8KB
#pragma unroll
    for (int j = 0; j < 8; ++j) lfs[t * 8 + j] = colsum[j];
    __syncthreads();
    if (t < 128) {
      float s = 0.f;
#pragma unroll
      for (int rg = 0; rg < 16; ++rg)
        s += lfs[(rg * 16 + (t >> 3)) * 8 + (t & 7)];
      atomicAdd(&gpart[(blockIdx.x & 15) * 128 + t], s);
    }
  }
}

// ---------------------------------------------------------------------------
// Readout (pooled sums in gpart[16][128])
// ---------------------------------------------------------------------------
__global__ __launch_bounds__(256) void readout_kernel(
    const float* __restrict__ gpart, const float* __restrict__ rW1,
    const float* __restrict__ rb1, const float* __restrict__ rW2,
    const float* __restrict__ rb2, const float* __restrict__ rW3,
    const float* __restrict__ rb3, float* __restrict__ outp, int N) {
  __shared__ float pooled[128];
  __shared__ float x1[64];
  __shared__ float x2[32];
  int t = threadIdx.x;
  if (t < 128) {
    float s = 0.f;
#pragma unroll
    for (int i = 0; i < 16; ++i) s += gpart[i * 128 + t];
    pooled[t] = s / (float)N;
  }
  __syncthreads();
  if (t < 64) {
    float s = rb1[t];
    for (int k = 0; k < 128; ++k) s = fmaf(pooled[k], rW1[k * 64 + t], s);
    x1[t] = fmaxf(s, 0.f);
  }
  __syncthreads();
  if (t < 32) {
    float s = rb2[t];
    for (int k = 0; k < 64; ++k) s = fmaf(x1[k], rW2[k * 32 + t], s);
    x2[t] = fmaxf(s, 0.f);
  }
  __syncthreads();
  if (t < 10) {
    float s = rb3[t];
    for (int k = 0; k < 32; ++k) s = fmaf(x2[k], rW3[k * 10 + t], s);
    outp[t] = s;
  }
}

extern "C" void kernel_launch(void* const* d_in, const int* in_sizes, int n_in,
                              void* d_out, int out_size, void* d_ws, size_t ws_size,
                              hipStream_t stream) {
  const float* h_in  = (const float*)d_in[0];
  const int*   src   = (const int*)d_in[1];
  const int*   dst   = (const int*)d_in[2];
  const float* enc_W = (const float*)d_in[3];
  const float* enc_b = (const float*)d_in[4];
  const float* W1    = (const float*)d_in[5];
  const float* b1    = (const float*)d_in[6];
  const float* W2    = (const float*)d_in[7];
  const float* b2    = (const float*)d_in[8];
  const float* rW1   = (const float*)d_in[9];
  const float* rb1   = (const float*)d_in[10];
  const float* rW2   = (const float*)d_in[11];
  const float* rb2   = (const float*)d_in[12];
  const float* rW3   = (const float*)d_in[13];
  const float* rb3   = (const float*)d_in[14];

  const int N = in_sizes[0] / 128;
  const int E = in_sizes[1];
  const int L = in_sizes[6] / 128;
  const int NB = (N + 127) >> 7;
  const int chunk = (E + NBLK - 1) / NBLK;

  char* ws = (char*)d_ws;
  size_t off = 0;
  auto alloc = [&](size_t bytes) {
    char* p = ws + off;
    off = (off + bytes + 511) & ~(size_t)511;
    return p;
  };
  unsigned short* h   = (unsigned short*)alloc((size_t)N * 128 * 2);
  unsigned short* hn  = (unsigned short*)alloc((size_t)N * 128 * 2);
  unsigned short* agg = (unsigned short*)alloc((size_t)N * 128 * 2);
  int* rowptr     = (int*)alloc((size_t)(N + 1) * 4);
  int* colidx     = (int*)alloc((size_t)E * 4);
  float* n1       = (float*)alloc((size_t)N * 4);
  float* n2       = (float*)alloc((size_t)N * 4);
  int* histG      = (int*)alloc((size_t)NB * NBLK * 4);
  int* bucketStart= (int*)alloc((size_t)(NB + 1) * 4);
  float* gpart    = (float*)alloc((size_t)16 * 128 * 4);
  unsigned short* encWh = (unsigned short*)alloc(16384 * 2);
  unsigned short* encWl = (unsigned short*)alloc(16384 * 2);
  unsigned short* W1th  = (unsigned short*)alloc((size_t)L * 32768 * 2);
  unsigned short* W1tl  = (unsigned short*)alloc((size_t)L * 32768 * 2);
  unsigned short* W2th  = (unsigned short*)alloc((size_t)L * 16384 * 2);
  unsigned short* W2tl  = (unsigned short*)alloc((size_t)L * 16384 * 2);
  unsigned int* pairs = (unsigned int*)alloc((size_t)E * 4);  // CSR scratch
  (void)ws_size; (void)n_in; (void)out_size;

  {
    int tot = 16384 + L * 32768 + L * 16384;
    prep_all<<<(tot + 255) / 256, 256, 0, stream>>>(
        enc_W, W1, W2, encWh, encWl, W1th, W1tl, W2th, W2tl, L);
  }

  bucketA<<<NBLK, 1024, 0, stream>>>(dst, histG, E, chunk, NB);
  bucketS<<<1, 1024, 0, stream>>>(histG, bucketStart, NB);
  bucketB<<<NBLK, 1024, 0, stream>>>(src, dst, histG, bucketStart, pairs, E,
                                     chunk, NB);
  bucketC<<<NB, 256, 0, stream>>>(pairs, bucketStart, rowptr, colidx, n1, n2, N, E);
  hipMemsetAsync(gpart, 0, 16 * 128 * 4, stream);

  const int gblocks = (N + 63) / 64;
  sage_mm<0><<<gblocks, 256, 0, stream>>>(h_in, nullptr, nullptr, encWh, encWl,
                                          nullptr, nullptr, enc_b, nullptr,
                                          n1, h, hn, nullptr, N);
  for (int l = 0; l < L; ++l) {
    agg_kernel<<<(N + 3) / 4, 256, 0, stream>>>(hn, rowptr, colidx, n2, agg, N);
    bool last = (l == L - 1);
    sage_mm<1><<<gblocks, 256, 0, stream>>>(
        nullptr, h, agg, W1th + (size_t)l * 32768, W1tl + (size_t)l * 32768,
        W2th + (size_t)l * 16384, W2tl + (size_t)l * 16384,
        b1 + l * 128, b2 + l * 128, n1, h,
        last ? nullptr : hn, last ? gpart : nullptr, N);
  }
  readout_kernel<<<1, 256, 0, stream>>>(gpart, rW1, rb1, rW2, rb2, rW3, rb3,
                                        (float*)d_out, N);
}

// Round 25
// 539.802 us; speedup vs baseline: 1.3862x; 1.0672x over previous
//
#include <hip/hip_runtime.h>
#include <math.h>

typedef short short8 __attribute__((ext_vector_type(8)));
typedef float f32x4 __attribute__((ext_vector_type(4)));

#define DEV static __device__ __forceinline__
#define NBLK 256   // blocks for bucket passes A/B

// ---- fp32 -> bf16 round-to-nearest-even; and hi/lo split -------------------
DEV unsigned int bf16h(float x) {
  unsigned int u = __float_as_uint(x);
  return (u + 0x7FFFu + ((u >> 16) & 1u)) >> 16;
}
DEV void split2(float x, unsigned int& h, unsigned int& l) {
  h = bf16h(x);
  float hf = __uint_as_float(h << 16);
  l = bf16h(x - hf);
}
DEV float b2f(unsigned int u) { return __uint_as_float(u << 16); }

// fragment-major W image index (ushort units) for element (c,k) of a
// [C=128 cols][K] transposed weight. Per 64-k subtile s (8192 shorts):
// [cg 0..3][ks 0..1][fc 0..1][lane 0..63][j 0..7] where
// col = cg*32 + fc*16 + (lane&15), k = s*64 + (ks*4 + (lane>>4))*8 + j.
DEV int fragidx(int c, int k) {
  int s = k >> 6, kk = k & 63;
  int ch = kk >> 3;            // 0..7 = ks*4 + g
  int ks = ch >> 2, g = ch & 3;
  int j = kk & 7;
  int cg = c >> 5, cc = c & 31;
  int fc = cc >> 4, rl = cc & 15;
  int lane = g * 16 + rl;
  return s * 8192 + cg * 2048 + ks * 1024 + fc * 512 + lane * 8 + j;
}

// ---------------------------------------------------------------------------
// CSR build via 128-row bucket sort (cross-XCD-write-friendly).
// pairs packed: src in bits 0..19, bucket-local dst in bits 20..26.
// ---------------------------------------------------------------------------
__global__ __launch_bounds__(1024) void bucketA(const int* __restrict__ dst,
                                                int* __restrict__ histG,
                                                int E, int chunk, int NB) {
  __shared__ int lh[1024];
  const int t = threadIdx.x;
  for (int i = t; i < NB; i += 1024) lh[i] = 0;
  __syncthreads();
  int s = blockIdx.x * chunk;
  int e = s + chunk; if (e > E) e = E;
  for (int i = s + t; i < e; i += 1024) atomicAdd(&lh[dst[i] >> 7], 1);
  __syncthreads();
  for (int b = t; b < NB; b += 1024) histG[b * NBLK + blockIdx.x] = lh[b];
}

__global__ __launch_bounds__(1024) void bucketS(int* __restrict__ histG,
                                                int* __restrict__ bucketStart,
                                                int NB) {
  __shared__ int btot[1024];
  __shared__ int wsum[16];
  const int t = threadIdx.x, lane = t & 63, wv = t >> 6;
  for (int b = wv; b < NB; b += 16) {
    int carry = 0;
#pragma unroll
    for (int c = 0; c < NBLK / 64; ++c) {
      int idx = b * NBLK + c * 64 + lane;
      int v = histG[idx];
      int x = v;
#pragma unroll
      for (int d = 1; d < 64; d <<= 1) {
        int y = __shfl_up(x, d);
        if (lane >= d) x += y;
      }
      histG[idx] = carry + (x - v);
      carry += __shfl(x, 63);
    }
    if (lane == 0) btot[b] = carry;
  }
  __syncthreads();
  int v = (t < NB) ? btot[t] : 0;
  int x = v;
#pragma unroll
  for (int d = 1; d < 64; d <<= 1) {
    int y = __shfl_up(x, d);
    if (lane >= d) x += y;
  }
  if (lane == 63) wsum[wv] = x;
  __syncthreads();
  if (wv == 0) {
    int y = (lane < 16) ? wsum[lane] : 0;
#pragma unroll
    for (int d = 1; d < 16; d <<= 1) {
      int z = __shfl_up(y, d);
      if (lane >= d) y += z;
    }
    if (lane < 16) wsum[lane] = y;
  }
  __syncthreads();
  int wbase = (wv > 0) ? wsum[wv - 1] : 0;
  int incl = wbase + x;
  if (t < NB) bucketStart[t] = incl - v;
  if (t == NB - 1) bucketStart[NB] = incl;
}

__global__ __launch_bounds__(1024) void bucketB(const int* __restrict__ src,
                                                const int* __restrict__ dstA,
                                                const int* __restrict__ histG,
                                                const int* __restrict__ bucketStart,
                                                unsigned int* __restrict__ pairs,
                                                int E, int chunk, int NB) {
  __shared__ int lbase[1024];
  __shared__ int lcnt[1024];
  const int t = threadIdx.x;
  for (int i = t; i < NB; i += 1024) {
    lbase[i] = bucketStart[i] + histG[i * NBLK + blockIdx.x];
    lcnt[i] = 0;
  }
  __syncthreads();
  int s = blockIdx.x * chunk;
  int e = s + chunk; if (e > E) e = E;
  for (int i = s + t; i < e; i += 1024) {
    int d = dstA[i];
    int b = d >> 7;
    int r = atomicAdd(&lcnt[b], 1);
    pairs[lbase[b] + r] = (unsigned int)src[i] | ((unsigned int)(d & 127) << 20);
  }
}

__global__ __launch_bounds__(256) void bucketC(const unsigned int* __restrict__ pairs,
                                               const int* __restrict__ bucketStart,
                                               int* __restrict__ rowptr,
                                               int* __restrict__ colidx,
                                               float* __restrict__ n1,
                                               float* __restrict__ n2,
                                               int N, int E) {
  __shared__ int degs[128];
  __shared__ int incl[128];
  __shared__ int cur[128];
  const int t = threadIdx.x, lane = t & 63;
  const int b = blockIdx.x;
  const int lo = b << 7;
  const int s0 = bucketStart[b], s1 = bucketStart[b + 1];
  if (t < 128) degs[t] = 0;
  __syncthreads();
  for (int i = s0 + t; i < s1; i += 256) atomicAdd(&degs[pairs[i] >> 20], 1);
  __syncthreads();
  int d = 0, x = 0;
  if (t < 128) {
    d = degs[t];
    x = d;
#pragma unroll
    for (int dd = 1; dd < 64; dd <<= 1) {
      int y = __shfl_up(x, dd);
      if (lane >= dd) x += y;
    }
    incl[t] = x;
  }
  __syncthreads();
  if (t >= 64 && t < 128) incl[t] += incl[63];
  __syncthreads();
  if (t < 128) {
    int excl = incl[t] - d;
    int row = lo + t;
    if (row < N) {
      rowptr[row] = s0 + excl;
      int dd2 = d < 1 ? 1 : d;
      float fd = (float)dd2;
      float r = 1.0f / sqrtf(fd);
      n1[row] = r;
      n2[row] = r / fd;
    }
    cur[t] = excl;
  }
  __syncthreads();
  for (int i = s0 + t; i < s1; i += 256) {
    unsigned int p = pairs[i];
    int off = atomicAdd(&cur[p >> 20], 1);
    colidx[s0 + off] = (int)(p & 0xFFFFFu);
  }
  if (b == 0 && t == 0) rowptr[N] = E;
}

// ---------------------------------------------------------------------------
// agg[i] = bf16( ( sum_e hn[col] ) * n2[i] )   hn = fp8(h*n1), 128B rows
// 8-wide batched gather; HW fp8->f32 converts.
// ---------------------------------------------------------------------------
__global__ __launch_bounds__(256) void agg_kernel(
    const unsigned char* __restrict__ hn, const int* __restrict__ rowptr,
    const int* __restrict__ colidx, const float* __restrict__ n2,
    unsigned short* __restrict__ agg, int N) {
  int wid = (blockIdx.x * 256 + threadIdx.x) >> 6;
  int lane = threadIdx.x & 63;
  if (wid >= N) return;
  int s = rowptr[wid], e = rowptr[wid + 1];
  float ax[4] = {0.f, 0.f, 0.f, 0.f};
  float ay[4] = {0.f, 0.f, 0.f, 0.f};
  for (int i = s; i < e; i += 8) {
    int c[8];
#pragma unroll
    for (int j = 0; j < 8; ++j) {
      int idx = i + j;
      c[j] = colidx[idx < e ? idx : e - 1];
    }
    unsigned short v[8];
#pragma unroll
    for (int j = 0; j < 8; ++j)
      v[j] = *(const unsigned short*)(hn + (size_t)c[j] * 128 + lane * 2);
#pragma unroll
    for (int j = 0; j < 8; ++j) {
      bool ok = (i + j) < e;
      float f0 = __builtin_amdgcn_cvt_f32_fp8((int)v[j], 0);
      float f1 = __builtin_amdgcn_cvt_f32_fp8((int)v[j], 1);
      ax[j & 3] += ok ? f0 : 0.f;
      ay[j & 3] += ok ? f1 : 0.f;
    }
  }
  float m = n2[wid];
  float axs = ((ax[0] + ax[1]) + (ax[2] + ax[3])) * m;
  float ays = ((ay[0] + ay[1]) + (ay[2] + ay[3])) * m;
  ((unsigned int*)agg)[(size_t)wid * 64 + lane] = bf16h(axs) | (bf16h(ays) << 16);
}

// ---------------------------------------------------------------------------
// Weight prep, single launch: transposed + hi/lo split into fragment-major
// images (per-wave coalesced 16B/lane register loads in sage_mm).
// ---------------------------------------------------------------------------
__global__ __launch_bounds__(256) void prep_all(
    const float* __restrict__ encW, const float* __restrict__ W1,
    const float* __restrict__ W2, unsigned short* __restrict__ encWh,
    unsigned short* __restrict__ encWl, unsigned short* __restrict__ W1th,
    unsigned short* __restrict__ W1tl, unsigned short* __restrict__ W2th,
    unsigned short* __restrict__ W2tl, int L) {
  int t = blockIdx.x * 256 + threadIdx.x;
  const int n1e = 16384;
  const int n2e = n1e + L * 32768;
  const int n3e = n2e + L * 16384;
  unsigned int h, l;
  if (t < n1e) {
    int c = t >> 7, k = t & 127;
    split2(encW[k * 128 + c], h, l);
    int di = fragidx(c, k);
    encWh[di] = (unsigned short)h; encWl[di] = (unsigned short)l;
  } else if (t < n2e) {
    int u = t - n1e;
    int ll = u >> 15, w = u & 32767;
    int c = w >> 8, k = w & 255;
    split2(W1[(size_t)ll * 32768 + k * 128 + c], h, l);
    int di = ll * 32768 + fragidx(c, k);
    W1th[di] = (unsigned short)h; W1tl[di] = (unsigned short)l;
  } else if (t < n3e) {
    int u = t - n2e;
    int ll = u >> 14, w = u & 16383;
    int c = w >> 7, k = w & 127;
    split2(W2[(size_t)ll * 16384 + k * 128 + c], h, l);
    int di = ll * 16384 + fragidx(c, k);
    W2th[di] = (unsigned short)h; W2tl[di] = (unsigned short)l;
  }
}

// ---------------------------------------------------------------------------
// Fused MFMA kernel: 256 threads (4 waves), 64-row x 128-col tile, BK=64.
// Double-buffered As (2 x 8KB), issue-early/write-late staging; W fragments
// register-loaded from L2-hot fragment-major images (no W LDS).
// KIND 0: h = bf16(fp32A @ W1 + b1). KIND 1: full fused layer (+ hn emit).
// hn emitted as fp8 e4m3 (128B rows) via HW cvt_pk_fp8.
// Last layer (gpart != nullptr): no h/hn writes; column sums LDS-reduced and
// atomically added into gpart[(blockIdx&15)*128 + col] (pooling fusion).
// ---------------------------------------------------------------------------
template <int KIND>
__global__ __launch_bounds__(256, 6) void sage_mm(
    const float* __restrict__ Af, const unsigned short* __restrict__ Ab,
    const unsigned short* __restrict__ A2b,
    const unsigned short* __restrict__ W1h, const unsigned short* __restrict__ W1l,
    const unsigned short* __restrict__ W2h, const unsigned short* __restrict__ W2l,
    const float* __restrict__ b1, const float* __restrict__ b2,
    const float* __restrict__ n1f,
    unsigned short* __restrict__ outb, unsigned char* __restrict__ hnout,
    float* __restrict__ gpart, int M) {
  __shared__ unsigned short lds[64 * 128];   // 16KB: buf0|buf1; Cs overlay
  unsigned short* buf0 = lds;
  unsigned short* buf1 = lds + 64 * 64;

  const int t = threadIdx.x;
  const int lane = t & 63;
  const int w = t >> 6;              // 0..3 = col-group
  const int rl = lane & 15, g = lane >> 4;
  const int cbase = w * 32;
  const int rowbase = blockIdx.x * 64;

  // ---- A staging split: load (to regs) / write (to LDS buf) ---------------
  auto loadAb = [&](const unsigned short* __restrict__ src, int k0, int4* v) {
    int r = t >> 2, kc = (t & 3) * 16;
    int grow = rowbase + r;
    const int4* s = (const int4*)(src + (size_t)grow * 128 + k0 + kc);
    v[0] = (grow < M) ? s[0] : make_int4(0, 0, 0, 0);
    v[1] = (grow < M) ? s[1] : make_int4(0, 0, 0, 0);
  };
  auto writeAb = [&](unsigned short* dst, const int4* v) {
    int r = t >> 2, kc = (t & 3) * 16;
#pragma unroll
    for (int j = 0; j < 2; ++j) {
      int ch = (kc >> 3) + j;
      int off = r * 64 * 2 + ((ch ^ (r & 7)) << 4);
      *(int4*)((char*)dst + off) = v[j];
    }
  };
  auto loadAf = [&](const float* __restrict__ src, int k0, float4* v) {
    int r = t >> 2, kc = (t & 3) * 16;
    int grow = rowbase + r;
    const float4* s = (const float4*)(src + (size_t)grow * 128 + k0 + kc);
#pragma unroll
    for (int j = 0; j < 4; ++j)
      v[j] = (grow < M) ? s[j] : make_float4(0.f, 0.f, 0.f, 0.f);
  };
  auto writeAf = [&](unsigned short* dst, const float4* v) {
    int r = t >> 2, kc = (t & 3) * 16;
#pragma unroll
    for (int j = 0; j < 4; ++j) {
      unsigned int h0 = bf16h(v[j].x), h1 = bf16h(v[j].y);
      unsigned int h2 = bf16h(v[j].z), h3 = bf16h(v[j].w);
      int k = kc + j * 4;
      int off = r * 128 + (((k >> 3) ^ (r & 7)) << 4) + (k & 7) * 2;
      *(int2*)((char*)dst + off) =
          make_int2((int)(h0 | (h1 << 16)), (int)(h2 | (h3 << 16)));
    }
  };

  f32x4 acc[4][2];
  auto zacc = [&]() {
#pragma unroll
    for (int i = 0; i < 4; ++i)
#pragma unroll
      for (int j = 0; j < 2; ++j) {
        f32x4 z = {0.f, 0.f, 0.f, 0.f};
        acc[i][j] = z;
      }
  };

  // kloop over one staged A-subtile in `as`; W fragments from global (L2-hot)
  auto kloop = [&](const unsigned short* imgh, const unsigned short* imgl,
                   int sub, const unsigned short* as) {
    const unsigned short* bh0 = imgh + sub * 8192 + w * 2048 + lane * 8;
    const unsigned short* bl0 = imgl + sub * 8192 + w * 2048 + lane * 8;
#pragma unroll
    for (int ks = 0; ks < 2; ++ks) {
      short8 aH[4], bH[2], bL[2];
#pragma unroll
      for (int fc = 0; fc < 2; ++fc) {
        bH[fc] = *(const short8*)(bh0 + ks * 1024 + fc * 512);
        bL[fc] = *(const short8*)(bl0 + ks * 1024 + fc * 512);
      }
#pragma unroll
      for (int fr = 0; fr < 4; ++fr) {
        int row = fr * 16 + rl;
        int off = row * 128 + (((ks * 4 + g) ^ (row & 7)) << 4);
        aH[fr] = *(const short8*)((const char*)as + off);
      }
#pragma unroll
      for (int fr = 0; fr < 4; ++fr)
#pragma unroll
        for (int fc = 0; fc < 2; ++fc) {
          acc[fr][fc] = __builtin_amdgcn_mfma_f32_16x16x32_bf16(
              aH[fr], bH[fc], acc[fr][fc], 0, 0, 0);
          acc[fr][fc] = __builtin_amdgcn_mfma_f32_16x16x32_bf16(
              aH[fr], bL[fc], acc[fr][fc], 0, 0, 0);
        }
    }
  };

  // z = relu(a + b1) staged (bf16) into `dst` for cols [c0,c0+64)
  auto zstage = [&](int c0, const f32x4 (&a)[4][2], unsigned short* dst) {
#pragma unroll
    for (int fc = 0; fc < 2; ++fc) {
      int col = cbase + fc * 16 + rl;
      unsigned int lc = (unsigned int)(col - c0);
      if (lc < 64u) {
        float bb = b1[col];
#pragma unroll
        for (int fr = 0; fr < 4; ++fr)
#pragma unroll
          for (int q = 0; q < 4; ++q) {
            int row = fr * 16 + g * 4 + q;
            float z = fmaxf(a[fr][fc][q] + bb, 0.f);
            int off = row * 128 + (((lc >> 3) ^ (row & 7)) << 4) + (lc & 7) * 2;
            *(unsigned short*)((char*)dst + off) = (unsigned short)bf16h(z);
          }
      }
    }
  };

  zacc();
  if (KIND == 0) {
    float4 vf[4];
    loadAf(Af, 0, vf); writeAf(buf0, vf);
    __syncthreads();
    loadAf(Af, 64, vf);                 // issue early
    kloop(W1h, W1l, 0, buf0);           // compute under load latency
    writeAf(buf1, vf);                  // write late
    __syncthreads();
    kloop(W1h, W1l, 1, buf1);
  } else {
    int4 va[2];
    loadAb(Ab, 0, va); writeAb(buf0, va);
    __syncthreads();
    loadAb(Ab, 64, va);
    kloop(W1h, W1l, 0, buf0);
    writeAb(buf1, va);
    __syncthreads();
    loadAb(A2b, 0, va);
    kloop(W1h, W1l, 1, buf1);
    writeAb(buf0, va);
    __syncthreads();
    loadAb(A2b, 64, va);
    kloop(W1h, W1l, 2, buf0);
    writeAb(buf1, va);
    __syncthreads();
    kloop(W1h, W1l, 3, buf1);           // GEMM1 complete in acc

    f32x4 acc1[4][2];
#pragma unroll
    for (int i = 0; i < 4; ++i)
#pragma unroll
      for (int j = 0; j < 2; ++j) acc1[i][j] = acc[i][j];
    zacc();
    zstage(0, acc1, buf0);              // buf0 free (last read P2); in-wave ok
    __syncthreads();
    zstage(64, acc1, buf1);             // buf1 reads all done (barrier above)
    kloop(W2h, W2l, 0, buf0);           // concurrent: reads buf0
    __syncthreads();
    kloop(W2h, W2l, 1, buf1);
  }

  // ---- epilogue: stage C in LDS (16KB overlay) -> coalesced writes ---------
  __syncthreads();
  unsigned short* Cs = lds;
  const float* bias = (KIND == 0) ? b1 : b2;
#pragma unroll
  for (int fc = 0; fc < 2; ++fc) {
    int col = cbase + fc * 16 + rl;
    float bb = bias[col];
#pragma unroll
    for (int fr = 0; fr < 4; ++fr)
#pragma unroll
      for (int q = 0; q < 4; ++q) {
        int row = fr * 16 + g * 4 + q;
        float val = acc[fr][fc][q] + bb;
        if (KIND == 1) val = fmaxf(val, 0.f);
        Cs[row * 128 + col] = (unsigned short)bf16h(val);
      }
  }
  __syncthreads();
  float colsum[8];
#pragma unroll
  for (int j = 0; j < 8; ++j) colsum[j] = 0.f;
#pragma unroll
  for (int p = 0; p < 4; ++p) {
    int bo = p * 4096 + t * 16;
    int row = bo >> 8;
    int grow = rowbase + row;
    if (grow >= M) continue;
    int4 z4 = *(const int4*)((const char*)Cs + bo);
    int* zp = (int*)&z4;
    if (KIND == 1) {
      int4 a4 = *(const int4*)((const char*)Ab + (size_t)grow * 256 + (bo & 255));
      const int* ap = (const int*)&a4;
#pragma unroll
      for (int u = 0; u < 4; ++u) {
        unsigned int za = (unsigned int)zp[u], aa = (unsigned int)ap[u];
        float vlo = b2f(za & 0xffffu) + b2f(aa & 0xffffu);
        float vhi = __uint_as_float(za & 0xffff0000u) +
                    __uint_as_float(aa & 0xffff0000u);
        zp[u] = (int)(bf16h(vlo) | (bf16h(vhi) << 16));
      }
    }
    if (KIND == 1 && gpart) {
      // pooling fusion: accumulate column sums; no global writes
#pragma unroll
      for (int u = 0; u < 4; ++u) {
        unsigned int za = (unsigned int)zp[u];
        colsum[u * 2] += b2f(za & 0xffffu);
        colsum[u * 2 + 1] += __uint_as_float(za & 0xffff0000u);
      }
      continue;
    }
    *(int4*)((char*)outb + (size_t)grow * 256 + (bo & 255)) = z4;
    {  // hn = fp8(h * n1[grow]) : 8 cols -> 8 bytes
      float n1r = n1f[grow];
      float f[8];
#pragma unroll
      for (int u = 0; u < 4; ++u) {
        unsigned int za = (unsigned int)zp[u];
        f[u * 2] = b2f(za & 0xffffu) * n1r;
        f[u * 2 + 1] = __uint_as_float(za & 0xffff0000u) * n1r;
      }
      int w01 = __builtin_amdgcn_cvt_pk_fp8_f32(f[0], f[1], 0, false);
      w01 = __builtin_amdgcn_cvt_pk_fp8_f32(f[2], f[3], w01, true);
      int w23 = __builtin_amdgcn_cvt_pk_fp8_f32(f[4], f[5], 0, false);
      w23 = __builtin_amdgcn_cvt_pk_fp8_f32(f[6], f[7], w23, true);
      *(int2*)(hnout + (size_t)grow * 128 + ((bo & 255) >> 1)) =
          make_int2(w01, w23);
    }
  }
  if (KIND == 1 && gpart) {
    // LDS reduce 16 row-groups -> 128 col sums -> scattered atomicAdd
    __syncthreads();
    float* lfs = (float*)lds;          // 256 threads x 8 floats = 8KB
#pragma unroll
    for (int j = 0; j < 8; ++j) lfs[t * 8 + j] = colsum[j];
    __syncthreads();
    if (t < 128) {
      float s = 0.f;
#pragma unroll
      for (int rg = 0; rg < 16; ++rg)
        s += lfs[(rg * 16 + (t >> 3)) * 8 + (t & 7)];
      atomicAdd(&gpart[(blockIdx.x & 15) * 128 + t], s);
    }
  }
}

// ---------------------------------------------------------------------------
// Readout (pooled sums in gpart[16][128])
// ---------------------------------------------------------------------------
__global__ __launch_bounds__(256) void readout_kernel(
    const float* __restrict__ gpart, const float* __restrict__ rW1,
    const float* __restrict__ rb1, const float* __restrict__ rW2,
    const float* __restrict__ rb2, const float* __restrict__ rW3,
    const float* __restrict__ rb3, float* __restrict__ outp, int N) {
  __shared__ float pooled[128];
  __shared__ float x1[64];
  __shared__ float x2[32];
  int t = threadIdx.x;
  if (t < 128) {
    float s = 0.f;
#pragma unroll
    for (int i = 0; i < 16; ++i) s += gpart[i * 128 + t];
    pooled[t] = s / (float)N;
  }
  __syncthreads();
  if (t < 64) {
    float s = rb1[t];
    for (int k = 0; k < 128; ++k) s = fmaf(pooled[k], rW1[k * 64 + t], s);
    x1[t] = fmaxf(s, 0.f);
  }
  __syncthreads();
  if (t < 32) {
    float s = rb2[t];
    for (int k = 0; k < 64; ++k) s = fmaf(x1[k], rW2[k * 32 + t], s);
    x2[t] = fmaxf(s, 0.f);
  }
  __syncthreads();
  if (t < 10) {
    float s = rb3[t];
    for (int k = 0; k < 32; ++k) s = fmaf(x2[k], rW3[k * 10 + t], s);
    outp[t] = s;
  }
}

extern "C" void kernel_launch(void* const* d_in, const int* in_sizes, int n_in,
                              void* d_out, int out_size, void* d_ws, size_t ws_size,
                              hipStream_t stream) {
  const float* h_in  = (const float*)d_in[0];
  const int*   src   = (const int*)d_in[1];
  const int*   dst   = (const int*)d_in[2];
  const float* enc_W = (const float*)d_in[3];
  const float* enc_b = (const float*)d_in[4];
  const float* W1    = (const float*)d_in[5];
  const float* b1    = (const float*)d_in[6];
  const float* W2    = (const float*)d_in[7];
  const float* b2    = (const float*)d_in[8];
  const float* rW1   = (const float*)d_in[9];
  const float* rb1   = (const float*)d_in[10];
  const float* rW2   = (const float*)d_in[11];
  const float* rb2   = (const float*)d_in[12];
  const float* rW3   = (const float*)d_in[13];
  const float* rb3   = (const float*)d_in[14];

  const int N = in_sizes[0] / 128;
  const int E = in_sizes[1];
  const int L = in_sizes[6] / 128;
  const int NB = (N + 127) >> 7;
  const int chunk = (E + NBLK - 1) / NBLK;

  char* ws = (char*)d_ws;
  size_t off = 0;
  auto alloc = [&](size_t bytes) {
    char* p = ws + off;
    off = (off + bytes + 511) & ~(size_t)511;
    return p;
  };
  unsigned short* h   = (unsigned short*)alloc((size_t)N * 128 * 2);
  unsigned char* hn   = (unsigned char*)alloc((size_t)N * 128);
  unsigned short* agg = (unsigned short*)alloc((size_t)N * 128 * 2);
  int* rowptr     = (int*)alloc((size_t)(N + 1) * 4);
  int* colidx     = (int*)alloc((size_t)E * 4);
  float* n1       = (float*)alloc((size_t)N * 4);
  float* n2       = (float*)alloc((size_t)N * 4);
  int* histG      = (int*)alloc((size_t)NB * NBLK * 4);
  int* bucketStart= (int*)alloc((size_t)(NB + 1) * 4);
  float* gpart    = (float*)alloc((size_t)16 * 128 * 4);
  unsigned short* encWh = (unsigned short*)alloc(16384 * 2);
  unsigned short* encWl = (unsigned short*)alloc(16384 * 2);
  unsigned short* W1th  = (unsigned short*)alloc((size_t)L * 32768 * 2);
  unsigned short* W1tl  = (unsigned short*)alloc((size_t)L * 32768 * 2);
  unsigned short* W2th  = (unsigned short*)alloc((size_t)L * 16384 * 2);
  unsigned short* W2tl  = (unsigned short*)alloc((size_t)L * 16384 * 2);
  unsigned int* pairs = (unsigned int*)alloc((size_t)E * 4);  // CSR scratch
  (void)ws_size; (void)n_in; (void)out_size;

  {
    int tot = 16384 + L * 32768 + L * 16384;
    prep_all<<<(tot + 255) / 256, 256, 0, stream>>>(
        enc_W, W1, W2, encWh, encWl, W1th, W1tl, W2th, W2tl, L);
  }

  bucketA<<<NBLK, 1024, 0, stream>>>(dst, histG, E, chunk, NB);
  bucketS<<<1, 1024, 0, stream>>>(histG, bucketStart, NB);
  bucketB<<<NBLK, 1024, 0, stream>>>(src, dst, histG, bucketStart, pairs, E,
                                     chunk, NB);
  bucketC<<<NB, 256, 0, stream>>>(pairs, bucketStart, rowptr, colidx, n1, n2, N, E);
  hipMemsetAsync(gpart, 0, 16 * 128 * 4, stream);

  const int gblocks = (N + 63) / 64;
  sage_mm<0><<<gblocks, 256, 0, stream>>>(h_in, nullptr, nullptr, encWh, encWl,
                                          nullptr, nullptr, enc_b, nullptr,
                                          n1, h, hn, nullptr, N);
  for (int l = 0; l < L; ++l) {
    agg_kernel<<<(N + 3) / 4, 256, 0, stream>>>(hn, rowptr, colidx, n2, agg, N);
    bool last = (l == L - 1);
    sage_mm<1><<<gblocks, 256, 0, stream>>>(
        nullptr, h, agg, W1th + (size_t)l * 32768, W1tl + (size_t)l * 32768,
        W2th + (size_t)l * 16384, W2tl + (size_t)l * 16384,
        b1 + l * 128, b2 + l * 128, n1, h,
        hn, last ? gpart : nullptr, N);
  }
  readout_kernel<<<1, 256, 0, stream>>>(gpart, rW1, rb1, rW2, rb2, rW3, rb3,
                                        (float*)d_out, N);
}

// Round 27
// 521.308 us; speedup vs baseline: 1.4354x; 1.0355x over previous
//
#include <hip/hip_runtime.h>
#include <math.h>

typedef short short8 __attribute__((ext_vector_type(8)));
typedef float f32x4 __attribute__((ext_vector_type(4)));

#define DEV static __device__ __forceinline__
#define NBLK 256   // blocks for bucket passes A/B

// ---- fp32 -> bf16 round-to-nearest-even; and hi/lo split -------------------
DEV unsigned int bf16h(float x) {
  unsigned int u = __float_as_uint(x);
  return (u + 0x7FFFu + ((u >> 16) & 1u)) >> 16;
}
DEV void split2(float x, unsigned int& h, unsigned int& l) {
  h = bf16h(x);
  float hf = __uint_as_float(h << 16);
  l = bf16h(x - hf);
}
DEV float b2f(unsigned int u) { return __uint_as_float(u << 16); }

// fragment-major W image index (ushort units) for element (c,k) of a
// [C=128 cols][K] transposed weight. Per 64-k subtile s (8192 shorts):
// [cg 0..3][ks 0..1][fc 0..1][lane 0..63][j 0..7] where
// col = cg*32 + fc*16 + (lane&15), k = s*64 + (ks*4 + (lane>>4))*8 + j.
DEV int fragidx(int c, int k) {
  int s = k >> 6, kk = k & 63;
  int ch = kk >> 3;            // 0..7 = ks*4 + g
  int ks = ch >> 2, g = ch & 3;
  int j = kk & 7;
  int cg = c >> 5, cc = c & 31;
  int fc = cc >> 4, rl = cc & 15;
  int lane = g * 16 + rl;
  return s * 8192 + cg * 2048 + ks * 1024 + fc * 512 + lane * 8 + j;
}

// ---------------------------------------------------------------------------
// CSR build via 128-row bucket sort (cross-XCD-write-friendly).
// pairs packed: src in bits 0..19, bucket-local dst in bits 20..26.
// ---------------------------------------------------------------------------
__global__ __launch_bounds__(1024) void bucketA(const int* __restrict__ dst,
                                                int* __restrict__ histG,
                                                int E, int chunk, int NB) {
  __shared__ int lh[1024];
  const int t = threadIdx.x;
  for (int i = t; i < NB; i += 1024) lh[i] = 0;
  __syncthreads();
  int s = blockIdx.x * chunk;
  int e = s + chunk; if (e > E) e = E;
  for (int i = s + t; i < e; i += 1024) atomicAdd(&lh[dst[i] >> 7], 1);
  __syncthreads();
  for (int b = t; b < NB; b += 1024) histG[b * NBLK + blockIdx.x] = lh[b];
}

__global__ __launch_bounds__(1024) void bucketS(int* __restrict__ histG,
                                                int* __restrict__ bucketStart,
                                                int NB) {
  __shared__ int btot[1024];
  __shared__ int wsum[16];
  const int t = threadIdx.x, lane = t & 63, wv = t >> 6;
  for (int b = wv; b < NB; b += 16) {
    int carry = 0;
#pragma unroll
    for (int c = 0; c < NBLK / 64; ++c) {
      int idx = b * NBLK + c * 64 + lane;
      int v = histG[idx];
      int x = v;
#pragma unroll
      for (int d = 1; d < 64; d <<= 1) {
        int y = __shfl_up(x, d);
        if (lane >= d) x += y;
      }
      histG[idx] = carry + (x - v);
      carry += __shfl(x, 63);
    }
    if (lane == 0) btot[b] = carry;
  }
  __syncthreads();
  int v = (t < NB) ? btot[t] : 0;
  int x = v;
#pragma unroll
  for (int d = 1; d < 64; d <<= 1) {
    int y = __shfl_up(x, d);
    if (lane >= d) x += y;
  }
  if (lane == 63) wsum[wv] = x;
  __syncthreads();
  if (wv == 0) {
    int y = (lane < 16) ? wsum[lane] : 0;
#pragma unroll
    for (int d = 1; d < 16; d <<= 1) {
      int z = __shfl_up(y, d);
      if (lane >= d) y += z;
    }
    if (lane < 16) wsum[lane] = y;
  }
  __syncthreads();
  int wbase = (wv > 0) ? wsum[wv - 1] : 0;
  int incl = wbase + x;
  if (t < NB) bucketStart[t] = incl - v;
  if (t == NB - 1) bucketStart[NB] = incl;
}

__global__ __launch_bounds__(1024) void bucketB(const int* __restrict__ src,
                                                const int* __restrict__ dstA,
                                                const int* __restrict__ histG,
                                                const int* __restrict__ bucketStart,
                                                unsigned int* __restrict__ pairs,
                                                int E, int chunk, int NB) {
  __shared__ int lbase[1024];
  __shared__ int lcnt[1024];
  const int t = threadIdx.x;
  for (int i = t; i < NB; i += 1024) {
    lbase[i] = bucketStart[i] + histG[i * NBLK + blockIdx.x];
    lcnt[i] = 0;
  }
  __syncthreads();
  int s = blockIdx.x * chunk;
  int e = s + chunk; if (e > E) e = E;
  for (int i = s + t; i < e; i += 1024) {
    int d = dstA[i];
    int b = d >> 7;
    int r = atomicAdd(&lcnt[b], 1);
    pairs[lbase[b] + r] = (unsigned int)src[i] | ((unsigned int)(d & 127) << 20);
  }
}

__global__ __launch_bounds__(256) void bucketC(const unsigned int* __restrict__ pairs,
                                               const int* __restrict__ bucketStart,
                                               int* __restrict__ rowptr,
                                               int* __restrict__ colidx,
                                               float* __restrict__ n1,
                                               float* __restrict__ n2,
                                               int N, int E) {
  __shared__ int degs[128];
  __shared__ int incl[128];
  __shared__ int cur[128];
  const int t = threadIdx.x, lane = t & 63;
  const int b = blockIdx.x;
  const int lo = b << 7;
  const int s0 = bucketStart[b], s1 = bucketStart[b + 1];
  if (t < 128) degs[t] = 0;
  __syncthreads();
  for (int i = s0 + t; i < s1; i += 256) atomicAdd(&degs[pairs[i] >> 20], 1);
  __syncthreads();
  int d = 0, x = 0;
  if (t < 128) {
    d = degs[t];
    x = d;
#pragma unroll
    for (int dd = 1; dd < 64; dd <<= 1) {
      int y = __shfl_up(x, dd);
      if (lane >= dd) x += y;
    }
    incl[t] = x;
  }
  __syncthreads();
  if (t >= 64 && t < 128) incl[t] += incl[63];
  __syncthreads();
  if (t < 128) {
    int excl = incl[t] - d;
    int row = lo + t;
    if (row < N) {
      rowptr[row] = s0 + excl;
      int dd2 = d < 1 ? 1 : d;
      float fd = (float)dd2;
      float r = 1.0f / sqrtf(fd);
      n1[row] = r;
      n2[row] = r / fd;
    }
    cur[t] = excl;
  }
  __syncthreads();
  for (int i = s0 + t; i < s1; i += 256) {
    unsigned int p = pairs[i];
    int off = atomicAdd(&cur[p >> 20], 1);
    colidx[s0 + off] = (int)(p & 0xFFFFFu);
  }
  if (b == 0 && t == 0) rowptr[N] = E;
}

// ---------------------------------------------------------------------------
// agg[i] = fp8( ( sum_e hn[col] ) * n2[i] )   hn = fp8(h*n1), 128B rows
// 8-wide batched gather; HW fp8 converts both directions.
// ---------------------------------------------------------------------------
__global__ __launch_bounds__(256) void agg_kernel(
    const unsigned char* __restrict__ hn, const int* __restrict__ rowptr,
    const int* __restrict__ colidx, const float* __restrict__ n2,
    unsigned char* __restrict__ agg, int N) {
  int wid = (blockIdx.x * 256 + threadIdx.x) >> 6;
  int lane = threadIdx.x & 63;
  if (wid >= N) return;
  int s = rowptr[wid], e = rowptr[wid + 1];
  float ax[4] = {0.f, 0.f, 0.f, 0.f};
  float ay[4] = {0.f, 0.f, 0.f, 0.f};
  for (int i = s; i < e; i += 8) {
    int c[8];
#pragma unroll
    for (int j = 0; j < 8; ++j) {
      int idx = i + j;
      c[j] = colidx[idx < e ? idx : e - 1];
    }
    unsigned short v[8];
#pragma unroll
    for (int j = 0; j < 8; ++j)
      v[j] = *(const unsigned short*)(hn + (size_t)c[j] * 128 + lane * 2);
#pragma unroll
    for (int j = 0; j < 8; ++j) {
      bool ok = (i + j) < e;
      float f0 = __builtin_amdgcn_cvt_f32_fp8((int)v[j], 0);
      float f1 = __builtin_amdgcn_cvt_f32_fp8((int)v[j], 1);
      ax[j & 3] += ok ? f0 : 0.f;
      ay[j & 3] += ok ? f1 : 0.f;
    }
  }
  float m = n2[wid];
  float axs = ((ax[0] + ax[1]) + (ax[2] + ax[3])) * m;
  float ays = ((ay[0] + ay[1]) + (ay[2] + ay[3])) * m;
  int p01 = __builtin_amdgcn_cvt_pk_fp8_f32(axs, ays, 0, false);
  *(unsigned short*)(agg + (size_t)wid * 128 + lane * 2) = (unsigned short)p01;
}

// ---------------------------------------------------------------------------
// Weight prep, single launch: transposed + hi/lo split into fragment-major
// images (per-wave coalesced 16B/lane register loads in sage_mm).
// ---------------------------------------------------------------------------
__global__ __launch_bounds__(256) void prep_all(
    const float* __restrict__ encW, const float* __restrict__ W1,
    const float* __restrict__ W2, unsigned short* __restrict__ encWh,
    unsigned short* __restrict__ encWl, unsigned short* __restrict__ W1th,
    unsigned short* __restrict__ W1tl, unsigned short* __restrict__ W2th,
    unsigned short* __restrict__ W2tl, int L) {
  int t = blockIdx.x * 256 + threadIdx.x;
  const int n1e = 16384;
  const int n2e = n1e + L * 32768;
  const int n3e = n2e + L * 16384;
  unsigned int h, l;
  if (t < n1e) {
    int c = t >> 7, k = t & 127;
    split2(encW[k * 128 + c], h, l);
    int di = fragidx(c, k);
    encWh[di] = (unsigned short)h; encWl[di] = (unsigned short)l;
  } else if (t < n2e) {
    int u = t - n1e;
    int ll = u >> 15, w = u & 32767;
    int c = w >> 8, k = w & 255;
    split2(W1[(size_t)ll * 32768 + k * 128 + c], h, l);
    int di = ll * 32768 + fragidx(c, k);
    W1th[di] = (unsigned short)h; W1tl[di] = (unsigned short)l;
  } else if (t < n3e) {
    int u = t - n2e;
    int ll = u >> 14, w = u & 16383;
    int c = w >> 7, k = w & 127;
    split2(W2[(size_t)ll * 16384 + k * 128 + c], h, l);
    int di = ll * 16384 + fragidx(c, k);
    W2th[di] = (unsigned short)h; W2tl[di] = (unsigned short)l;
  }
}

// ---------------------------------------------------------------------------
// Fused MFMA kernel: 256 threads (4 waves), 64-row x 128-col tile, BK=64.
// Double-buffered As (2 x 8KB), issue-early/write-late staging; W fragments
// register-loaded from L2-hot fragment-major images (no W LDS).
// KIND 0: h = bf16(fp32A @ W1 + b1). KIND 1: full fused layer (+ hn emit).
// agg input is fp8 (reg-staged with HW convert to bf16 LDS tiles).
// hn emitted as fp8 e4m3 (128B rows) via HW cvt_pk_fp8.
// Last layer (gpart != nullptr): no h/hn writes; column sums LDS-reduced and
// atomically added into gpart[(blockIdx&15)*128 + col] (pooling fusion).
// ---------------------------------------------------------------------------
template <int KIND>
__global__ __launch_bounds__(256, 6) void sage_mm(
    const float* __restrict__ Af, const unsigned short* __restrict__ Ab,
    const unsigned char* __restrict__ A2q,
    const unsigned short* __restrict__ W1h, const unsigned short* __restrict__ W1l,
    const unsigned short* __restrict__ W2h, const unsigned short* __restrict__ W2l,
    const float* __restrict__ b1, const float* __restrict__ b2,
    const float* __restrict__ n1f,
    unsigned short* __restrict__ outb, unsigned char* __restrict__ hnout,
    float* __restrict__ gpart, int M) {
  __shared__ unsigned short lds[64 * 128];   // 16KB: buf0|buf1; Cs overlay
  unsigned short* buf0 = lds;
  unsigned short* buf1 = lds + 64 * 64;

  const int t = threadIdx.x;
  const int lane = t & 63;
  const int w = t >> 6;              // 0..3 = col-group
  const int rl = lane & 15, g = lane >> 4;
  const int cbase = w * 32;
  const int rowbase = blockIdx.x * 64;

  // ---- A staging split: load (to regs) / write (to LDS buf) ---------------
  auto loadAb = [&](const unsigned short* __restrict__ src, int k0, int4* v) {
    int r = t >> 2, kc = (t & 3) * 16;
    int grow = rowbase + r;
    const int4* s = (const int4*)(src + (size_t)grow * 128 + k0 + kc);
    v[0] = (grow < M) ? s[0] : make_int4(0, 0, 0, 0);
    v[1] = (grow < M) ? s[1] : make_int4(0, 0, 0, 0);
  };
  auto writeAb = [&](unsigned short* dst, const int4* v) {
    int r = t >> 2, kc = (t & 3) * 16;
#pragma unroll
    for (int j = 0; j < 2; ++j) {
      int ch = (kc >> 3) + j;
      int off = r * 128 + ((ch ^ (r & 7)) << 4);
      *(int4*)((char*)dst + off) = v[j];
    }
  };
  // fp8 agg subtile: 16 fp8 (16B) per thread
  auto loadA8 = [&](const unsigned char* __restrict__ src, int k0, int4* v) {
    int r = t >> 2, kc = (t & 3) * 16;
    int grow = rowbase + r;
    const int4* s = (const int4*)(src + (size_t)grow * 128 + k0 + kc);
    v[0] = (grow < M) ? s[0] : make_int4(0, 0, 0, 0);
  };
  auto writeA8 = [&](unsigned short* dst, const int4* v) {
    int r = t >> 2, kc = (t & 3) * 16;
    const int* bw = (const int*)v;
#pragma unroll
    for (int j = 0; j < 2; ++j) {
      unsigned short ob[8];
#pragma unroll
      for (int u = 0; u < 2; ++u) {
        int word = bw[j * 2 + u];
        ob[u * 4 + 0] = (unsigned short)bf16h(__builtin_amdgcn_cvt_f32_fp8(word, 0));
        ob[u * 4 + 1] = (unsigned short)bf16h(__builtin_amdgcn_cvt_f32_fp8(word, 1));
        ob[u * 4 + 2] = (unsigned short)bf16h(__builtin_amdgcn_cvt_f32_fp8(word, 2));
        ob[u * 4 + 3] = (unsigned short)bf16h(__builtin_amdgcn_cvt_f32_fp8(word, 3));
      }
      int ch = (kc >> 3) + j;
      int off = r * 128 + ((ch ^ (r & 7)) << 4);
      *(int4*)((char*)dst + off) = *(const int4*)ob;
    }
  };
  auto loadAf = [&](const float* __restrict__ src, int k0, float4* v) {
    int r = t >> 2, kc = (t & 3) * 16;
    int grow = rowbase + r;
    const float4* s = (const float4*)(src + (size_t)grow * 128 + k0 + kc);
#pragma unroll
    for (int j = 0; j < 4; ++j)
      v[j] = (grow < M) ? s[j] : make_float4(0.f, 0.f, 0.f, 0.f);
  };
  auto writeAf = [&](unsigned short* dst, const float4* v) {
    int r = t >> 2, kc = (t & 3) * 16;
#pragma unroll
    for (int j = 0; j < 4; ++j) {
      unsigned int h0 = bf16h(v[j].x), h1 = bf16h(v[j].y);
      unsigned int h2 = bf16h(v[j].z), h3 = bf16h(v[j].w);
      int k = kc + j * 4;
      int off = r * 128 + (((k >> 3) ^ (r & 7)) << 4) + (k & 7) * 2;
      *(int2*)((char*)dst + off) =
          make_int2((int)(h0 | (h1 << 16)), (int)(h2 | (h3 << 16)));
    }
  };

  f32x4 acc[4][2];
  auto zacc = [&]() {
#pragma unroll
    for (int i = 0; i < 4; ++i)
#pragma unroll
      for (int j = 0; j < 2; ++j) {
        f32x4 z = {0.f, 0.f, 0.f, 0.f};
        acc[i][j] = z;
      }
  };

  // kloop over one staged A-subtile in `as`; W fragments from global (L2-hot)
  auto kloop = [&](const unsigned short* imgh, const unsigned short* imgl,
                   int sub, const unsigned short* as) {
    const unsigned short* bh0 = imgh + sub * 8192 + w * 2048 + lane * 8;
    const unsigned short* bl0 = imgl + sub * 8192 + w * 2048 + lane * 8;
#pragma unroll
    for (int ks = 0; ks < 2; ++ks) {
      short8 aH[4], bH[2], bL[2];
#pragma unroll
      for (int fc = 0; fc < 2; ++fc) {
        bH[fc] = *(const short8*)(bh0 + ks * 1024 + fc * 512);
        bL[fc] = *(const short8*)(bl0 + ks * 1024 + fc * 512);
      }
#pragma unroll
      for (int fr = 0; fr < 4; ++fr) {
        int row = fr * 16 + rl;
        int off = row * 128 + (((ks * 4 + g) ^ (row & 7)) << 4);
        aH[fr] = *(const short8*)((const char*)as + off);
      }
#pragma unroll
      for (int fr = 0; fr < 4; ++fr)
#pragma unroll
        for (int fc = 0; fc < 2; ++fc) {
          acc[fr][fc] = __builtin_amdgcn_mfma_f32_16x16x32_bf16(
              aH[fr], bH[fc], acc[fr][fc], 0, 0, 0);
          acc[fr][fc] = __builtin_amdgcn_mfma_f32_16x16x32_bf16(
              aH[fr], bL[fc], acc[fr][fc], 0, 0, 0);
        }
    }
  };

  // z = relu(a + b1) staged (bf16) into `dst` for cols [c0,c0+64)
  auto zstage = [&](int c0, const f32x4 (&a)[4][2], unsigned short* dst) {
#pragma unroll
    for (int fc = 0; fc < 2; ++fc) {
      int col = cbase + fc * 16 + rl;
      unsigned int lc = (unsigned int)(col - c0);
      if (lc < 64u) {
        float bb = b1[col];
#pragma unroll
        for (int fr = 0; fr < 4; ++fr)
#pragma unroll
          for (int q = 0; q < 4; ++q) {
            int row = fr * 16 + g * 4 + q;
            float z = fmaxf(a[fr][fc][q] + bb, 0.f);
            int off = row * 128 + (((lc >> 3) ^ (row & 7)) << 4) + (lc & 7) * 2;
            *(unsigned short*)((char*)dst + off) = (unsigned short)bf16h(z);
          }
      }
    }
  };

  zacc();
  if (KIND == 0) {
    float4 vf[4];
    loadAf(Af, 0, vf); writeAf(buf0, vf);
    __syncthreads();
    loadAf(Af, 64, vf);                 // issue early
    kloop(W1h, W1l, 0, buf0);           // compute under load latency
    writeAf(buf1, vf);                  // write late
    __syncthreads();
    kloop(W1h, W1l, 1, buf1);
  } else {
    int4 va[2];
    loadAb(Ab, 0, va); writeAb(buf0, va);
    __syncthreads();
    loadAb(Ab, 64, va);
    kloop(W1h, W1l, 0, buf0);
    writeAb(buf1, va);
    __syncthreads();
    loadA8(A2q, 0, va);
    kloop(W1h, W1l, 1, buf1);
    writeA8(buf0, va);
    __syncthreads();
    loadA8(A2q, 64, va);
    kloop(W1h, W1l, 2, buf0);
    writeA8(buf1, va);
    __syncthreads();
    kloop(W1h, W1l, 3, buf1);           // GEMM1 complete in acc

    f32x4 acc1[4][2];
#pragma unroll
    for (int i = 0; i < 4; ++i)
#pragma unroll
      for (int j = 0; j < 2; ++j) acc1[i][j] = acc[i][j];
    zacc();
    zstage(0, acc1, buf0);              // buf0 free (last read P2); in-wave ok
    __syncthreads();
    zstage(64, acc1, buf1);             // buf1 reads all done (barrier above)
    kloop(W2h, W2l, 0, buf0);           // concurrent: reads buf0
    __syncthreads();
    kloop(W2h, W2l, 1, buf1);
  }

  // ---- epilogue: stage C in LDS (16KB overlay) -> coalesced writes ---------
  __syncthreads();
  unsigned short* Cs = lds;
  const float* bias = (KIND == 0) ? b1 : b2;
#pragma unroll
  for (int fc = 0; fc < 2; ++fc) {
    int col = cbase + fc * 16 + rl;
    float bb = bias[col];
#pragma unroll
    for (int fr = 0; fr < 4; ++fr)
#pragma unroll
      for (int q = 0; q < 4; ++q) {
        int row = fr * 16 + g * 4 + q;
        float val = acc[fr][fc][q] + bb;
        if (KIND == 1) val = fmaxf(val, 0.f);
        Cs[row * 128 + col] = (unsigned short)bf16h(val);
      }
  }
  __syncthreads();
  float colsum[8];
#pragma unroll
  for (int j = 0; j < 8; ++j) colsum[j] = 0.f;
#pragma unroll
  for (int p = 0; p < 4; ++p) {
    int bo = p * 4096 + t * 16;
    int row = bo >> 8;
    int grow = rowbase + row;
    if (grow >= M) continue;
    int4 z4 = *(const int4*)((const char*)Cs + bo);
    int* zp = (int*)&z4;
    if (KIND == 1) {
      int4 a4 = *(const int4*)((const char*)Ab + (size_t)grow * 256 + (bo & 255));
      const int* ap = (const int*)&a4;
#pragma unroll
      for (int u = 0; u < 4; ++u) {
        unsigned int za = (unsigned int)zp[u], aa = (unsigned int)ap[u];
        float vlo = b2f(za & 0xffffu) + b2f(aa & 0xffffu);
        float vhi = __uint_as_float(za & 0xffff0000u) +
                    __uint_as_float(aa & 0xffff0000u);
        zp[u] = (int)(bf16h(vlo) | (bf16h(vhi) << 16));
      }
    }
    if (KIND == 1 && gpart) {
      // pooling fusion: accumulate column sums; no global writes
#pragma unroll
      for (int u = 0; u < 4; ++u) {
        unsigned int za = (unsigned int)zp[u];
        colsum[u * 2] += b2f(za & 0xffffu);
        colsum[u * 2 + 1] += __uint_as_float(za & 0xffff0000u);
      }
      continue;
    }
    *(int4*)((char*)outb + (size_t)grow * 256 + (bo & 255)) = z4;
    {  // hn = fp8(h * n1[grow]) : 8 cols -> 8 bytes
      float n1r = n1f[grow];
      float f[8];
#pragma unroll
      for (int u = 0; u < 4; ++u) {
        unsigned int za = (unsigned int)zp[u];
        f[u * 2] = b2f(za & 0xffffu) * n1r;
        f[u * 2 + 1] = __uint_as_float(za & 0xffff0000u) * n1r;
      }
      int w01 = __builtin_amdgcn_cvt_pk_fp8_f32(f[0], f[1], 0, false);
      w01 = __builtin_amdgcn_cvt_pk_fp8_f32(f[2], f[3], w01, true);
      int w23 = __builtin_amdgcn_cvt_pk_fp8_f32(f[4], f[5], 0, false);
      w23 = __builtin_amdgcn_cvt_pk_fp8_f32(f[6], f[7], w23, true);
      *(int2*)(hnout + (size_t)grow * 128 + ((bo & 255) >> 1)) =
          make_int2(w01, w23);
    }
  }
  if (KIND == 1 && gpart) {
    // LDS reduce 16 row-groups -> 128 col sums -> scattered atomicAdd
    __syncthreads();
    float* lfs = (float*)lds;          // 256 threads x 8 floats = 8KB
#pragma unroll
    for (int j = 0; j < 8; ++j) lfs[t * 8 + j] = colsum[j];
    __syncthreads();
    if (t < 128) {
      float s = 0.f;
#pragma unroll
      for (int rg = 0; rg < 16; ++rg)
        s += lfs[(rg * 16 + (t >> 3)) * 8 + (t & 7)];
      atomicAdd(&gpart[(blockIdx.x & 15) * 128 + t], s);
    }
  }
}

// ---------------------------------------------------------------------------
// Readout (pooled sums in gpart[16][128])
// ---------------------------------------------------------------------------
__global__ __launch_bounds__(256) void readout_kernel(
    const float* __restrict__ gpart, const float* __restrict__ rW1,
    const float* __restrict__ rb1, const float* __restrict__ rW2,
    const float* __restrict__ rb2, const float* __restrict__ rW3,
    const float* __restrict__ rb3, float* __restrict__ outp, int N) {
  __shared__ float pooled[128];
  __shared__ float x1[64];
  __shared__ float x2[32];
  int t = threadIdx.x;
  if (t < 128) {
    float s = 0.f;
#pragma unroll
    for (int i = 0; i < 16; ++i) s += gpart[i * 128 + t];
    pooled[t] = s / (float)N;
  }
  __syncthreads();
  if (t < 64) {
    float s = rb1[t];
    for (int k = 0; k < 128; ++k) s = fmaf(pooled[k], rW1[k * 64 + t], s);
    x1[t] = fmaxf(s, 0.f);
  }
  __syncthreads();
  if (t < 32) {
    float s = rb2[t];
    for (int k = 0; k < 64; ++k) s = fmaf(x1[k], rW2[k * 32 + t], s);
    x2[t] = fmaxf(s, 0.f);
  }
  __syncthreads();
  if (t < 10) {
    float s = rb3[t];
    for (int k = 0; k < 32; ++k) s = fmaf(x2[k], rW3[k * 10 + t], s);
    outp[t] = s;
  }
}

extern "C" void kernel_launch(void* const* d_in, const int* in_sizes, int n_in,
                              void* d_out, int out_size, void* d_ws, size_t ws_size,
                              hipStream_t stream) {
  const float* h_in  = (const float*)d_in[0];
  const int*   src   = (const int*)d_in[1];
  const int*   dst   = (const int*)d_in[2];
  const float* enc_W = (const float*)d_in[3];
  const float* enc_b = (const float*)d_in[4];
  const float* W1    = (const float*)d_in[5];
  const float* b1    = (const float*)d_in[6];
  const float* W2    = (const float*)d_in[7];
  const float* b2    = (const float*)d_in[8];
  const float* rW1   = (const float*)d_in[9];
  const float* rb1   = (const float*)d_in[10];
  const float* rW2   = (const float*)d_in[11];
  const float* rb2   = (const float*)d_in[12];
  const float* rW3   = (const float*)d_in[13];
  const float* rb3   = (const float*)d_in[14];

  const int N = in_sizes[0] / 128;
  const int E = in_sizes[1];
  const int L = in_sizes[6] / 128;
  const int NB = (N + 127) >> 7;
  const int chunk = (E + NBLK - 1) / NBLK;

  char* ws = (char*)d_ws;
  size_t off = 0;
  auto alloc = [&](size_t bytes) {
    char* p = ws + off;
    off = (off + bytes + 511) & ~(size_t)511;
    return p;
  };
  unsigned short* h   = (unsigned short*)alloc((size_t)N * 128 * 2);
  unsigned char* hn   = (unsigned char*)alloc((size_t)N * 128);
  unsigned char* agg  = (unsigned char*)alloc((size_t)N * 128);
  int* rowptr     = (int*)alloc((size_t)(N + 1) * 4);
  int* colidx     = (int*)alloc((size_t)E * 4);
  float* n1       = (float*)alloc((size_t)N * 4);
  float* n2       = (float*)alloc((size_t)N * 4);
  int* histG      = (int*)alloc((size_t)NB * NBLK * 4);
  int* bucketStart= (int*)alloc((size_t)(NB + 1) * 4);
  float* gpart    = (float*)alloc((size_t)16 * 128 * 4);
  unsigned short* encWh = (unsigned short*)alloc(16384 * 2);
  unsigned short* encWl = (unsigned short*)alloc(16384 * 2);
  unsigned short* W1th  = (unsigned short*)alloc((size_t)L * 32768 * 2);
  unsigned short* W1tl  = (unsigned short*)alloc((size_t)L * 32768 * 2);
  unsigned short* W2th  = (unsigned short*)alloc((size_t)L * 16384 * 2);
  unsigned short* W2tl  = (unsigned short*)alloc((size_t)L * 16384 * 2);
  unsigned int* pairs = (unsigned int*)alloc((size_t)E * 4);  // CSR scratch
  (void)ws_size; (void)n_in; (void)out_size;

  {
    int tot = 16384 + L * 32768 + L * 16384;
    prep_all<<<(tot + 255) / 256, 256, 0, stream>>>(
        enc_W, W1, W2, encWh, encWl, W1th, W1tl, W2th, W2tl, L);
  }

  bucketA<<<NBLK, 1024, 0, stream>>>(dst, histG, E, chunk, NB);
  bucketS<<<1, 1024, 0, stream>>>(histG, bucketStart, NB);
  bucketB<<<NBLK, 1024, 0, stream>>>(src, dst, histG, bucketStart, pairs, E,
                                     chunk, NB);
  bucketC<<<NB, 256, 0, stream>>>(pairs, bucketStart, rowptr, colidx, n1, n2, N, E);
  (void)hipMemsetAsync(gpart, 0, 16 * 128 * 4, stream);

  const int gblocks = (N + 63) / 64;
  sage_mm<0><<<gblocks, 256, 0, stream>>>(h_in, nullptr, nullptr, encWh, encWl,
                                          nullptr, nullptr, enc_b, nullptr,
                                          n1, h, hn, nullptr, N);
  for (int l = 0; l < L; ++l) {
    agg_kernel<<<(N + 3) / 4, 256, 0, stream>>>(hn, rowptr, colidx, n2, agg, N);
    bool last = (l == L - 1);
    sage_mm<1><<<gblocks, 256, 0, stream>>>(
        nullptr, h, agg, W1th + (size_t)l * 32768, W1tl + (size_t)l * 32768,
        W2th + (size_t)l * 16384, W2tl + (size_t)l * 16384,
        b1 + l * 128, b2 + l * 128, n1, h,
        hn, last ? gpart : nullptr, N);
  }
  readout_kernel<<<1, 256, 0, stream>>>(gpart, rW1, rb1, rW2, rb2, rW3, rb3,
                                        (float*)d_out, N);
}

// Round 28
// 459.464 us; speedup vs baseline: 1.6286x; 1.1346x over previous
//
#include <hip/hip_runtime.h>
#include <math.h>

typedef short short8 __attribute__((ext_vector_type(8)));
typedef float f32x4 __attribute__((ext_vector_type(4)));

#define DEV static __device__ __forceinline__
#define NBLK 256   // blocks for bucket passes A/B

// ---- fp32 -> bf16 round-to-nearest-even; and hi/lo split -------------------
DEV unsigned int bf16h(float x) {
  unsigned int u = __float_as_uint(x);
  return (u + 0x7FFFu + ((u >> 16) & 1u)) >> 16;
}
DEV void split2(float x, unsigned int& h, unsigned int& l) {
  h = bf16h(x);
  float hf = __uint_as_float(h << 16);
  l = bf16h(x - hf);
}
DEV float b2f(unsigned int u) { return __uint_as_float(u << 16); }

// fragment-major W image index (ushort units) for element (c,k) of a
// [C=128 cols][K] transposed weight. Per 64-k subtile s (8192 shorts):
// [cg 0..3][ks 0..1][fc 0..1][lane 0..63][j 0..7] where
// col = cg*32 + fc*16 + (lane&15), k = s*64 + (ks*4 + (lane>>4))*8 + j.
DEV int fragidx(int c, int k) {
  int s = k >> 6, kk = k & 63;
  int ch = kk >> 3;            // 0..7 = ks*4 + g
  int ks = ch >> 2, g = ch & 3;
  int j = kk & 7;
  int cg = c >> 5, cc = c & 31;
  int fc = cc >> 4, rl = cc & 15;
  int lane = g * 16 + rl;
  return s * 8192 + cg * 2048 + ks * 1024 + fc * 512 + lane * 8 + j;
}

// ---------------------------------------------------------------------------
// CSR build via 128-row bucket sort (cross-XCD-write-friendly).
// pairs packed: src in bits 0..19, bucket-local dst in bits 20..26.
// ---------------------------------------------------------------------------
__global__ __launch_bounds__(1024) void bucketA(const int* __restrict__ dst,
                                                int* __restrict__ histG,
                                                int E, int chunk, int NB) {
  __shared__ int lh[1024];
  const int t = threadIdx.x;
  for (int i = t; i < NB; i += 1024) lh[i] = 0;
  __syncthreads();
  int s = blockIdx.x * chunk;
  int e = s + chunk; if (e > E) e = E;
  for (int i = s + t; i < e; i += 1024) atomicAdd(&lh[dst[i] >> 7], 1);
  __syncthreads();
  for (int b = t; b < NB; b += 1024) histG[b * NBLK + blockIdx.x] = lh[b];
}

// S1: one wave per bucket — scan its NBLK per-block counts, write exclusive
// prefixes back and the bucket total to btot[b].  (parallel across buckets)
__global__ __launch_bounds__(1024) void bucketS1(int* __restrict__ histG,
                                                 int* __restrict__ btot,
                                                 int NB) {
  int wv = blockIdx.x * 16 + (threadIdx.x >> 6);
  int lane = threadIdx.x & 63;
  if (wv >= NB) return;
  int carry = 0;
#pragma unroll
  for (int c = 0; c < NBLK / 64; ++c) {
    int idx = wv * NBLK + c * 64 + lane;
    int v = histG[idx];
    int x = v;
#pragma unroll
    for (int d = 1; d < 64; d <<= 1) {
      int y = __shfl_up(x, d);
      if (lane >= d) x += y;
    }
    histG[idx] = carry + (x - v);
    carry += __shfl(x, 63);
  }
  if (lane == 0) btot[wv] = carry;
}

// S2: single block — exclusive scan of NB bucket totals -> bucketStart.
__global__ __launch_bounds__(1024) void bucketS2(const int* __restrict__ btot,
                                                 int* __restrict__ bucketStart,
                                                 int NB) {
  __shared__ int wsum[16];
  const int t = threadIdx.x, lane = t & 63, wv = t >> 6;
  int v = (t < NB) ? btot[t] : 0;
  int x = v;
#pragma unroll
  for (int d = 1; d < 64; d <<= 1) {
    int y = __shfl_up(x, d);
    if (lane >= d) x += y;
  }
  if (lane == 63) wsum[wv] = x;
  __syncthreads();
  if (wv == 0) {
    int y = (lane < 16) ? wsum[lane] : 0;
#pragma unroll
    for (int d = 1; d < 16; d <<= 1) {
      int z = __shfl_up(y, d);
      if (lane >= d) y += z;
    }
    if (lane < 16) wsum[lane] = y;
  }
  __syncthreads();
  int wbase = (wv > 0) ? wsum[wv - 1] : 0;
  int incl = wbase + x;
  if (t < NB) bucketStart[t] = incl - v;
  if (t == NB - 1) bucketStart[NB] = incl;
}

__global__ __launch_bounds__(1024) void bucketB(const int* __restrict__ src,
                                                const int* __restrict__ dstA,
                                                const int* __restrict__ histG,
                                                const int* __restrict__ bucketStart,
                                                unsigned int* __restrict__ pairs,
                                                int E, int chunk, int NB) {
  __shared__ int lbase[1024];
  __shared__ int lcnt[1024];
  const int t = threadIdx.x;
  for (int i = t; i < NB; i += 1024) {
    lbase[i] = bucketStart[i] + histG[i * NBLK + blockIdx.x];
    lcnt[i] = 0;
  }
  __syncthreads();
  int s = blockIdx.x * chunk;
  int e = s + chunk; if (e > E) e = E;
  for (int i = s + t; i < e; i += 1024) {
    int d = dstA[i];
    int b = d >> 7;
    int r = atomicAdd(&lcnt[b], 1);
    pairs[lbase[b] + r] = (unsigned int)src[i] | ((unsigned int)(d & 127) << 20);
  }
}

__global__ __launch_bounds__(256) void bucketC(const unsigned int* __restrict__ pairs,
                                               const int* __restrict__ bucketStart,
                                               int* __restrict__ rowptr,
                                               int* __restrict__ colidx,
                                               float* __restrict__ n1,
                                               float* __restrict__ n2,
                                               int N, int E) {
  __shared__ int degs[128];
  __shared__ int incl[128];
  __shared__ int cur[128];
  const int t = threadIdx.x, lane = t & 63;
  const int b = blockIdx.x;
  const int lo = b << 7;
  const int s0 = bucketStart[b], s1 = bucketStart[b + 1];
  if (t < 128) degs[t] = 0;
  __syncthreads();
  for (int i = s0 + t; i < s1; i += 256) atomicAdd(&degs[pairs[i] >> 20], 1);
  __syncthreads();
  int d = 0, x = 0;
  if (t < 128) {
    d = degs[t];
    x = d;
#pragma unroll
    for (int dd = 1; dd < 64; dd <<= 1) {
      int y = __shfl_up(x, dd);
      if (lane >= dd) x += y;
    }
    incl[t] = x;
  }
  __syncthreads();
  if (t >= 64 && t < 128) incl[t] += incl[63];
  __syncthreads();
  if (t < 128) {
    int excl = incl[t] - d;
    int row = lo + t;
    if (row < N) {
      rowptr[row] = s0 + excl;
      int dd2 = d < 1 ? 1 : d;
      float fd = (float)dd2;
      float r = 1.0f / sqrtf(fd);
      n1[row] = r;
      n2[row] = r / fd;
    }
    cur[t] = excl;
  }
  __syncthreads();
  for (int i = s0 + t; i < s1; i += 256) {
    unsigned int p = pairs[i];
    int off = atomicAdd(&cur[p >> 20], 1);
    colidx[s0 + off] = (int)(p & 0xFFFFFu);
  }
  if (b == 0 && t == 0) rowptr[N] = E;
}

// ---------------------------------------------------------------------------
// agg[i] = fp8( ( sum_e hn[col] ) * n2[i] )   hn = fp8(h*n1), 128B rows
// 8-wide batched gather; HW fp8 converts both directions.
// ---------------------------------------------------------------------------
__global__ __launch_bounds__(256) void agg_kernel(
    const unsigned char* __restrict__ hn, const int* __restrict__ rowptr,
    const int* __restrict__ colidx, const float* __restrict__ n2,
    unsigned char* __restrict__ agg, int N) {
  int wid = (blockIdx.x * 256 + threadIdx.x) >> 6;
  int lane = threadIdx.x & 63;
  if (wid >= N) return;
  int s = rowptr[wid], e = rowptr[wid + 1];
  float ax[4] = {0.f, 0.f, 0.f, 0.f};
  float ay[4] = {0.f, 0.f, 0.f, 0.f};
  for (int i = s; i < e; i += 8) {
    int c[8];
#pragma unroll
    for (int j = 0; j < 8; ++j) {
      int idx = i + j;
      c[j] = colidx[idx < e ? idx : e - 1];
    }
    unsigned short v[8];
#pragma unroll
    for (int j = 0; j < 8; ++j)
      v[j] = *(const unsigned short*)(hn + (size_t)c[j] * 128 + lane * 2);
#pragma unroll
    for (int j = 0; j < 8; ++j) {
      bool ok = (i + j) < e;
      float f0 = __builtin_amdgcn_cvt_f32_fp8((int)v[j], 0);
      float f1 = __builtin_amdgcn_cvt_f32_fp8((int)v[j], 1);
      ax[j & 3] += ok ? f0 : 0.f;
      ay[j & 3] += ok ? f1 : 0.f;
    }
  }
  float m = n2[wid];
  float axs = ((ax[0] + ax[1]) + (ax[2] + ax[3])) * m;
  float ays = ((ay[0] + ay[1]) + (ay[2] + ay[3])) * m;
  int p01 = __builtin_amdgcn_cvt_pk_fp8_f32(axs, ays, 0, false);
  *(unsigned short*)(agg + (size_t)wid * 128 + lane * 2) = (unsigned short)p01;
}

// ---------------------------------------------------------------------------
// Weight prep, single launch: transposed + hi/lo split into fragment-major
// images (per-wave coalesced 16B/lane register loads in sage_mm).
// ---------------------------------------------------------------------------
__global__ __launch_bounds__(256) void prep_all(
    const float* __restrict__ encW, const float* __restrict__ W1,
    const float* __restrict__ W2, unsigned short* __restrict__ encWh,
    unsigned short* __restrict__ encWl, unsigned short* __restrict__ W1th,
    unsigned short* __restrict__ W1tl, unsigned short* __restrict__ W2th,
    unsigned short* __restrict__ W2tl, int L) {
  int t = blockIdx.x * 256 + threadIdx.x;
  const int n1e = 16384;
  const int n2e = n1e + L * 32768;
  const int n3e = n2e + L * 16384;
  unsigned int h, l;
  if (t < n1e) {
    int c = t >> 7, k = t & 127;
    split2(encW[k * 128 + c], h, l);
    int di = fragidx(c, k);
    encWh[di] = (unsigned short)h; encWl[di] = (unsigned short)l;
  } else if (t < n2e) {
    int u = t - n1e;
    int ll = u >> 15, w = u & 32767;
    int c = w >> 8, k = w & 255;
    split2(W1[(size_t)ll * 32768 + k * 128 + c], h, l);
    int di = ll * 32768 + fragidx(c, k);
    W1th[di] = (unsigned short)h; W1tl[di] = (unsigned short)l;
  } else if (t < n3e) {
    int u = t - n2e;
    int ll = u >> 14, w = u & 16383;
    int c = w >> 7, k = w & 127;
    split2(W2[(size_t)ll * 16384 + k * 128 + c], h, l);
    int di = ll * 16384 + fragidx(c, k);
    W2th[di] = (unsigned short)h; W2tl[di] = (unsigned short)l;
  }
}

// ---------------------------------------------------------------------------
// Fused MFMA kernel: 256 threads (4 waves), 64-row x 128-col tile, BK=64.
// Double-buffered As (2 x 8KB), issue-early/write-late staging; W fragments
// register-loaded from L2-hot fragment-major images (no W LDS).
// KIND 0: h = bf16(fp32A @ W1 + b1). KIND 1: full fused layer (+ hn emit).
// agg input is fp8 (reg-staged with HW convert to bf16 LDS tiles).
// hn emitted as fp8 e4m3 (128B rows) via HW cvt_pk_fp8.
// Last layer (gpart != nullptr): no h/hn writes; column sums LDS-reduced and
// atomically added into gpart[(blockIdx&15)*128 + col] (pooling fusion).
// ---------------------------------------------------------------------------
template <int KIND>
__global__ __launch_bounds__(256, 6) void sage_mm(
    const float* __restrict__ Af, const unsigned short* __restrict__ Ab,
    const unsigned char* __restrict__ A2q,
    const unsigned short* __restrict__ W1h, const unsigned short* __restrict__ W1l,
    const unsigned short* __restrict__ W2h, const unsigned short* __restrict__ W2l,
    const float* __restrict__ b1, const float* __restrict__ b2,
    const float* __restrict__ n1f,
    unsigned short* __restrict__ outb, unsigned char* __restrict__ hnout,
    float* __restrict__ gpart, int M) {
  __shared__ unsigned short lds[64 * 128];   // 16KB: buf0|buf1; Cs overlay
  unsigned short* buf0 = lds;
  unsigned short* buf1 = lds + 64 * 64;

  const int t = threadIdx.x;
  const int lane = t & 63;
  const int w = t >> 6;              // 0..3 = col-group
  const int rl = lane & 15, g = lane >> 4;
  const int cbase = w * 32;
  const int rowbase = blockIdx.x * 64;

  // ---- A staging split: load (to regs) / write (to LDS buf) ---------------
  auto loadAb = [&](const unsigned short* __restrict__ src, int k0, int4* v) {
    int r = t >> 2, kc = (t & 3) * 16;
    int grow = rowbase + r;
    const int4* s = (const int4*)(src + (size_t)grow * 128 + k0 + kc);
    v[0] = (grow < M) ? s[0] : make_int4(0, 0, 0, 0);
    v[1] = (grow < M) ? s[1] : make_int4(0, 0, 0, 0);
  };
  auto writeAb = [&](unsigned short* dst, const int4* v) {
    int r = t >> 2, kc = (t & 3) * 16;
#pragma unroll
    for (int j = 0; j < 2; ++j) {
      int ch = (kc >> 3) + j;
      int off = r * 128 + ((ch ^ (r & 7)) << 4);
      *(int4*)((char*)dst + off) = v[j];
    }
  };
  // fp8 agg subtile: 16 fp8 (16B) per thread
  auto loadA8 = [&](const unsigned char* __restrict__ src, int k0, int4* v) {
    int r = t >> 2, kc = (t & 3) * 16;
    int grow = rowbase + r;
    const int4* s = (const int4*)(src + (size_t)grow * 128 + k0 + kc);
    v[0] = (grow < M) ? s[0] : make_int4(0, 0, 0, 0);
  };
  auto writeA8 = [&](unsigned short* dst, const int4* v) {
    int r = t >> 2, kc = (t & 3) * 16;
    const int* bw = (const int*)v;
#pragma unroll
    for (int j = 0; j < 2; ++j) {
      unsigned short ob[8];
#pragma unroll
      for (int u = 0; u < 2; ++u) {
        int word = bw[j * 2 + u];
        ob[u * 4 + 0] = (unsigned short)bf16h(__builtin_amdgcn_cvt_f32_fp8(word, 0));
        ob[u * 4 + 1] = (unsigned short)bf16h(__builtin_amdgcn_cvt_f32_fp8(word, 1));
        ob[u * 4 + 2] = (unsigned short)bf16h(__builtin_amdgcn_cvt_f32_fp8(word, 2));
        ob[u * 4 + 3] = (unsigned short)bf16h(__builtin_amdgcn_cvt_f32_fp8(word, 3));
      }
      int ch = (kc >> 3) + j;
      int off = r * 128 + ((ch ^ (r & 7)) << 4);
      *(int4*)((char*)dst + off) = *(const int4*)ob;
    }
  };
  auto loadAf = [&](const float* __restrict__ src, int k0, float4* v) {
    int r = t >> 2, kc = (t & 3) * 16;
    int grow = rowbase + r;
    const float4* s = (const float4*)(src + (size_t)grow * 128 + k0 + kc);
#pragma unroll
    for (int j = 0; j < 4; ++j)
      v[j] = (grow < M) ? s[j] : make_float4(0.f, 0.f, 0.f, 0.f);
  };
  auto writeAf = [&](unsigned short* dst, const float4* v) {
    int r = t >> 2, kc = (t & 3) * 16;
#pragma unroll
    for (int j = 0; j < 4; ++j) {
      unsigned int h0 = bf16h(v[j].x), h1 = bf16h(v[j].y);
      unsigned int h2 = bf16h(v[j].z), h3 = bf16h(v[j].w);
      int k = kc + j * 4;
      int off = r * 128 + (((k >> 3) ^ (r & 7)) << 4) + (k & 7) * 2;
      *(int2*)((char*)dst + off) =
          make_int2((int)(h0 | (h1 << 16)), (int)(h2 | (h3 << 16)));
    }
  };

  f32x4 acc[4][2];
  auto zacc = [&]() {
#pragma unroll
    for (int i = 0; i < 4; ++i)
#pragma unroll
      for (int j = 0; j < 2; ++j) {
        f32x4 z = {0.f, 0.f, 0.f, 0.f};
        acc[i][j] = z;
      }
  };

  // kloop over one staged A-subtile in `as`; W fragments from global (L2-hot)
  auto kloop = [&](const unsigned short* imgh, const unsigned short* imgl,
                   int sub, const unsigned short* as) {
    const unsigned short* bh0 = imgh + sub * 8192 + w * 2048 + lane * 8;
    const unsigned short* bl0 = imgl + sub * 8192 + w * 2048 + lane * 8;
#pragma unroll
    for (int ks = 0; ks < 2; ++ks) {
      short8 aH[4], bH[2], bL[2];
#pragma unroll
      for (int fc = 0; fc < 2; ++fc) {
        bH[fc] = *(const short8*)(bh0 + ks * 1024 + fc * 512);
        bL[fc] = *(const short8*)(bl0 + ks * 1024 + fc * 512);
      }
#pragma unroll
      for (int fr = 0; fr < 4; ++fr) {
        int row = fr * 16 + rl;
        int off = row * 128 + (((ks * 4 + g) ^ (row & 7)) << 4);
        aH[fr] = *(const short8*)((const char*)as + off);
      }
#pragma unroll
      for (int fr = 0; fr < 4; ++fr)
#pragma unroll
        for (int fc = 0; fc < 2; ++fc) {
          acc[fr][fc] = __builtin_amdgcn_mfma_f32_16x16x32_bf16(
              aH[fr], bH[fc], acc[fr][fc], 0, 0, 0);
          acc[fr][fc] = __builtin_amdgcn_mfma_f32_16x16x32_bf16(
              aH[fr], bL[fc], acc[fr][fc], 0, 0, 0);
        }
    }
  };

  // z = relu(a + b1) staged (bf16) into `dst` for cols [c0,c0+64)
  auto zstage = [&](int c0, const f32x4 (&a)[4][2], unsigned short* dst) {
#pragma unroll
    for (int fc = 0; fc < 2; ++fc) {
      int col = cbase + fc * 16 + rl;
      unsigned int lc = (unsigned int)(col - c0);
      if (lc < 64u) {
        float bb = b1[col];
#pragma unroll
        for (int fr = 0; fr < 4; ++fr)
#pragma unroll
          for (int q = 0; q < 4; ++q) {
            int row = fr * 16 + g * 4 + q;
            float z = fmaxf(a[fr][fc][q] + bb, 0.f);
            int off = row * 128 + (((lc >> 3) ^ (row & 7)) << 4) + (lc & 7) * 2;
            *(unsigned short*)((char*)dst + off) = (unsigned short)bf16h(z);
          }
      }
    }
  };

  zacc();
  if (KIND == 0) {
    float4 vf[4];
    loadAf(Af, 0, vf); writeAf(buf0, vf);
    __syncthreads();
    loadAf(Af, 64, vf);                 // issue early
    kloop(W1h, W1l, 0, buf0);           // compute under load latency
    writeAf(buf1, vf);                  // write late
    __syncthreads();
    kloop(W1h, W1l, 1, buf1);
  } else {
    int4 va[2];
    loadAb(Ab, 0, va); writeAb(buf0, va);
    __syncthreads();
    loadAb(Ab, 64, va);
    kloop(W1h, W1l, 0, buf0);
    writeAb(buf1, va);
    __syncthreads();
    loadA8(A2q, 0, va);
    kloop(W1h, W1l, 1, buf1);
    writeA8(buf0, va);
    __syncthreads();
    loadA8(A2q, 64, va);
    kloop(W1h, W1l, 2, buf0);
    writeA8(buf1, va);
    __syncthreads();
    kloop(W1h, W1l, 3, buf1);           // GEMM1 complete in acc

    f32x4 acc1[4][2];
#pragma unroll
    for (int i = 0; i < 4; ++i)
#pragma unroll
      for (int j = 0; j < 2; ++j) acc1[i][j] = acc[i][j];
    zacc();
    zstage(0, acc1, buf0);              // buf0 free (last read P2); in-wave ok
    __syncthreads();
    zstage(64, acc1, buf1);             // buf1 reads all done (barrier above)
    kloop(W2h, W2l, 0, buf0);           // concurrent: reads buf0
    __syncthreads();
    kloop(W2h, W2l, 1, buf1);
  }

  // ---- epilogue: stage C in LDS (16KB overlay) -> coalesced writes ---------
  __syncthreads();
  unsigned short* Cs = lds;
  const float* bias = (KIND == 0) ? b1 : b2;
#pragma unroll
  for (int fc = 0; fc < 2; ++fc) {
    int col = cbase + fc * 16 + rl;
    float bb = bias[col];
#pragma unroll
    for (int fr = 0; fr < 4; ++fr)
#pragma unroll
      for (int q = 0; q < 4; ++q) {
        int row = fr * 16 + g * 4 + q;
        float val = acc[fr][fc][q] + bb;
        if (KIND == 1) val = fmaxf(val, 0.f);
        Cs[row * 128 + col] = (unsigned short)bf16h(val);
      }
  }
  __syncthreads();
  float colsum[8];
#pragma unroll
  for (int j = 0; j < 8; ++j) colsum[j] = 0.f;
#pragma unroll
  for (int p = 0; p < 4; ++p) {
    int bo = p * 4096 + t * 16;
    int row = bo >> 8;
    int grow = rowbase + row;
    if (grow >= M) continue;
    int4 z4 = *(const int4*)((const char*)Cs + bo);
    int* zp = (int*)&z4;
    if (KIND == 1) {
      int4 a4 = *(const int4*)((const char*)Ab + (size_t)grow * 256 + (bo & 255));
      const int* ap = (const int*)&a4;
#pragma unroll
      for (int u = 0; u < 4; ++u) {
        unsigned int za = (unsigned int)zp[u], aa = (unsigned int)ap[u];
        float vlo = b2f(za & 0xffffu) + b2f(aa & 0xffffu);
        float vhi = __uint_as_float(za & 0xffff0000u) +
                    __uint_as_float(aa & 0xffff0000u);
        zp[u] = (int)(bf16h(vlo) | (bf16h(vhi) << 16));
      }
    }
    if (KIND == 1 && gpart) {
      // pooling fusion: accumulate column sums; no global writes
#pragma unroll
      for (int u = 0; u < 4; ++u) {
        unsigned int za = (unsigned int)zp[u];
        colsum[u * 2] += b2f(za & 0xffffu);
        colsum[u * 2 + 1] += __uint_as_float(za & 0xffff0000u);
      }
      continue;
    }
    *(int4*)((char*)outb + (size_t)grow * 256 + (bo & 255)) = z4;
    {  // hn = fp8(h * n1[grow]) : 8 cols -> 8 bytes
      float n1r = n1f[grow];
      float f[8];
#pragma unroll
      for (int u = 0; u < 4; ++u) {
        unsigned int za = (unsigned int)zp[u];
        f[u * 2] = b2f(za & 0xffffu) * n1r;
        f[u * 2 + 1] = __uint_as_float(za & 0xffff0000u) * n1r;
      }
      int w01 = __builtin_amdgcn_cvt_pk_fp8_f32(f[0], f[1], 0, false);
      w01 = __builtin_amdgcn_cvt_pk_fp8_f32(f[2], f[3], w01, true);
      int w23 = __builtin_amdgcn_cvt_pk_fp8_f32(f[4], f[5], 0, false);
      w23 = __builtin_amdgcn_cvt_pk_fp8_f32(f[6], f[7], w23, true);
      *(int2*)(hnout + (size_t)grow * 128 + ((bo & 255) >> 1)) =
          make_int2(w01, w23);
    }
  }
  if (KIND == 1 && gpart) {
    // LDS reduce 16 row-groups -> 128 col sums -> scattered atomicAdd
    __syncthreads();
    float* lfs = (float*)lds;          // 256 threads x 8 floats = 8KB
#pragma unroll
    for (int j = 0; j < 8; ++j) lfs[t * 8 + j] = colsum[j];
    __syncthreads();
    if (t < 128) {
      float s = 0.f;
#pragma unroll
      for (int rg = 0; rg < 16; ++rg)
        s += lfs[(rg * 16 + (t >> 3)) * 8 + (t & 7)];
      atomicAdd(&gpart[(blockIdx.x & 15) * 128 + t], s);
    }
  }
}

// ---------------------------------------------------------------------------
// Readout (pooled sums in gpart[16][128])
// ---------------------------------------------------------------------------
__global__ __launch_bounds__(256) void readout_kernel(
    const float* __restrict__ gpart, const float* __restrict__ rW1,
    const float* __restrict__ rb1, const float* __restrict__ rW2,
    const float* __restrict__ rb2, const float* __restrict__ rW3,
    const float* __restrict__ rb3, float* __restrict__ outp, int N) {
  __shared__ float pooled[128];
  __shared__ float x1[64];
  __shared__ float x2[32];
  int t = threadIdx.x;
  if (t < 128) {
    float s = 0.f;
#pragma unroll
    for (int i = 0; i < 16; ++i) s += gpart[i * 128 + t];
    pooled[t] = s / (float)N;
  }
  __syncthreads();
  if (t < 64) {
    float s = rb1[t];
    for (int k = 0; k < 128; ++k) s = fmaf(pooled[k], rW1[k * 64 + t], s);
    x1[t] = fmaxf(s, 0.f);
  }
  __syncthreads();
  if (t < 32) {
    float s = rb2[t];
    for (int k = 0; k < 64; ++k) s = fmaf(x1[k], rW2[k * 32 + t], s);
    x2[t] = fmaxf(s, 0.f);
  }
  __syncthreads();
  if (t < 10) {
    float s = rb3[t];
    for (int k = 0; k < 32; ++k) s = fmaf(x2[k], rW3[k * 10 + t], s);
    outp[t] = s;
  }
}

extern "C" void kernel_launch(void* const* d_in, const int* in_sizes, int n_in,
                              void* d_out, int out_size, void* d_ws, size_t ws_size,
                              hipStream_t stream) {
  const float* h_in  = (const float*)d_in[0];
  const int*   src   = (const int*)d_in[1];
  const int*   dst   = (const int*)d_in[2];
  const float* enc_W = (const float*)d_in[3];
  const float* enc_b = (const float*)d_in[4];
  const float* W1    = (const float*)d_in[5];
  const float* b1    = (const float*)d_in[6];
  const float* W2    = (const float*)d_in[7];
  const float* b2    = (const float*)d_in[8];
  const float* rW1   = (const float*)d_in[9];
  const float* rb1   = (const float*)d_in[10];
  const float* rW2   = (const float*)d_in[11];
  const float* rb2   = (const float*)d_in[12];
  const float* rW3   = (const float*)d_in[13];
  const float* rb3   = (const float*)d_in[14];

  const int N = in_sizes[0] / 128;
  const int E = in_sizes[1];
  const int L = in_sizes[6] / 128;
  const int NB = (N + 127) >> 7;
  const int chunk = (E + NBLK - 1) / NBLK;

  char* ws = (char*)d_ws;
  size_t off = 0;
  auto alloc = [&](size_t bytes) {
    char* p = ws + off;
    off = (off + bytes + 511) & ~(size_t)511;
    return p;
  };
  unsigned short* h   = (unsigned short*)alloc((size_t)N * 128 * 2);
  unsigned char* hn   = (unsigned char*)alloc((size_t)N * 128);
  unsigned char* agg  = (unsigned char*)alloc((size_t)N * 128);
  int* rowptr     = (int*)alloc((size_t)(N + 1) * 4);
  int* colidx     = (int*)alloc((size_t)E * 4);
  float* n1       = (float*)alloc((size_t)N * 4);
  float* n2       = (float*)alloc((size_t)N * 4);
  int* histG      = (int*)alloc((size_t)NB * NBLK * 4);
  int* btot       = (int*)alloc((size_t)NB * 4);
  int* bucketStart= (int*)alloc((size_t)(NB + 1) * 4);
  float* gpart    = (float*)alloc((size_t)16 * 128 * 4);
  unsigned short* encWh = (unsigned short*)alloc(16384 * 2);
  unsigned short* encWl = (unsigned short*)alloc(16384 * 2);
  unsigned short* W1th  = (unsigned short*)alloc((size_t)L * 32768 * 2);
  unsigned short* W1tl  = (unsigned short*)alloc((size_t)L * 32768 * 2);
  unsigned short* W2th  = (unsigned short*)alloc((size_t)L * 16384 * 2);
  unsigned short* W2tl  = (unsigned short*)alloc((size_t)L * 16384 * 2);
  unsigned int* pairs = (unsigned int*)alloc((size_t)E * 4);  // CSR scratch
  (void)ws_size; (void)n_in; (void)out_size;

  {
    int tot = 16384 + L * 32768 + L * 16384;
    prep_all<<<(tot + 255) / 256, 256, 0, stream>>>(
        enc_W, W1, W2, encWh, encWl, W1th, W1tl, W2th, W2tl, L);
  }

  bucketA<<<NBLK, 1024, 0, stream>>>(dst, histG, E, chunk, NB);
  bucketS1<<<(NB + 15) / 16, 1024, 0, stream>>>(histG, btot, NB);
  bucketS2<<<1, 1024, 0, stream>>>(btot, bucketStart, NB);
  bucketB<<<NBLK, 1024, 0, stream>>>(src, dst, histG, bucketStart, pairs, E,
                                     chunk, NB);
  bucketC<<<NB, 256, 0, stream>>>(pairs, bucketStart, rowptr, colidx, n1, n2, N, E);
  (void)hipMemsetAsync(gpart, 0, 16 * 128 * 4, stream);

  const int gblocks = (N + 63) / 64;
  sage_mm<0><<<gblocks, 256, 0, stream>>>(h_in, nullptr, nullptr, encWh, encWl,
                                          nullptr, nullptr, enc_b, nullptr,
                                          n1, h, hn, nullptr, N);
  for (int l = 0; l < L; ++l) {
    agg_kernel<<<(N + 3) / 4, 256, 0, stream>>>(hn, rowptr, colidx, n2, agg, N);
    bool last = (l == L - 1);
    sage_mm<1><<<gblocks, 256, 0, stream>>>(
        nullptr, h, agg, W1th + (size_t)l * 32768, W1tl + (size_t)l * 32768,
        W2th + (size_t)l * 16384, W2tl + (size_t)l * 16384,
        b1 + l * 128, b2 + l * 128, n1, h,
        hn, last ? gpart : nullptr, N);
  }
  readout_kernel<<<1, 256, 0, stream>>>(gpart, rW1, rb1, rW2, rb2, rW3, rb3,
                                        (float*)d_out, N);
}